// Round 2
// baseline (27107.803 us; speedup 1.0000x reference)
//
#include <hip/hip_runtime.h>
#include <hip/hip_bf16.h>
#include <math.h>

// Problem dims
constexpr int B_   = 8;
constexpr int T_   = 16;
constexpr int N_   = 196;
constexpr int C_   = 768;
constexpr int H_   = 8;
constexpr int D_   = 96;
constexpr int M_   = 196;    // MEM
constexpr int HID_ = 3072;
constexpr int ROWS_ = B_ * N_;   // 1568 == B_*M_

// ---------------- block reduction (256 threads) ----------------
__device__ __forceinline__ float block_reduce_sum256(float v, float* sdata) {
    int tid = threadIdx.x;
    sdata[tid] = v;
    __syncthreads();
    for (int s = 128; s > 0; s >>= 1) {
        if (tid < s) sdata[tid] += sdata[tid + s];
        __syncthreads();
    }
    float r = sdata[0];
    __syncthreads();
    return r;
}

// ---------------- LN of one frame -> dst [ROWS, C] (fp32) ----------------
__global__ __launch_bounds__(256) void ln_frame_kernel(
    const float* __restrict__ cur, int t,
    const float* __restrict__ w, const float* __restrict__ bia,
    float* __restrict__ dst)
{
    __shared__ float sdata[256];
    int row = blockIdx.x;              // b*N + n
    int b = row / N_, n = row % N_;
    const float* src = cur + (((size_t)b * T_ + t) * N_ + n) * C_;
    float x[3];
    float sum = 0.f, sumsq = 0.f;
#pragma unroll
    for (int i = 0; i < 3; i++) {
        int c = threadIdx.x + i * 256;
        x[i] = src[c];
        sum += x[i]; sumsq += x[i] * x[i];
    }
    sum = block_reduce_sum256(sum, sdata);
    sumsq = block_reduce_sum256(sumsq, sdata);
    float mu = sum * (1.0f / C_);
    float var = sumsq * (1.0f / C_) - mu * mu;
    float rs = rsqrtf(var + 1e-5f);
#pragma unroll
    for (int i = 0; i < 3; i++) {
        int c = threadIdx.x + i * 256;
        dst[(size_t)row * C_ + c] = (x[i] - mu) * rs * w[c] + bia[c];
    }
}

// ---------------- ap[b,c] = mean_m mem[b,m,c] ----------------
__global__ __launch_bounds__(768) void ap_kernel(const float* __restrict__ mem,
                                                 float* __restrict__ ap)
{
    int b = blockIdx.x;
    int c = threadIdx.x;   // 768 threads
    const float* p = mem + (size_t)b * M_ * C_ + c;
    float s = 0.f;
    for (int m = 0; m < M_; m++) s += p[(size_t)m * C_];
    ap[b * C_ + c] = s * (1.0f / M_);
}

// ---------------- cat[row, 0:C] = LN(frame t), cat[row, C:2C] = ap[b] ----------------
__global__ __launch_bounds__(256) void build_cat_kernel(
    const float* __restrict__ cur, int t,
    const float* __restrict__ w, const float* __restrict__ bia,
    const float* __restrict__ ap, float* __restrict__ cat)
{
    __shared__ float sdata[256];
    int row = blockIdx.x;
    int b = row / N_, n = row % N_;
    const float* src = cur + (((size_t)b * T_ + t) * N_ + n) * C_;
    float x[3];
    float sum = 0.f, sumsq = 0.f;
#pragma unroll
    for (int i = 0; i < 3; i++) {
        int c = threadIdx.x + i * 256;
        x[i] = src[c];
        sum += x[i]; sumsq += x[i] * x[i];
    }
    sum = block_reduce_sum256(sum, sdata);
    sumsq = block_reduce_sum256(sumsq, sdata);
    float mu = sum * (1.0f / C_);
    float var = sumsq * (1.0f / C_) - mu * mu;
    float rs = rsqrtf(var + 1e-5f);
    float* dstrow = cat + (size_t)row * (2 * C_);
#pragma unroll
    for (int i = 0; i < 3; i++) {
        int c = threadIdx.x + i * 256;
        dstrow[c] = (x[i] - mu) * rs * w[c] + bia[c];
        dstrow[C_ + c] = ap[b * C_ + c];
    }
}

// ---------------- generic tiled SGEMM: C[M,N] = A[M,K] * W[K,N] + bias, opt GELU ----------------
template <int GELU>
__global__ __launch_bounds__(256) void gemm_kernel(
    const float* __restrict__ A, const float* __restrict__ W,
    const float* __restrict__ bias, float* __restrict__ Co,
    int Mr, int K, int Nc)
{
    __shared__ float As[16][68];   // [k][m]
    __shared__ float Ws[16][68];   // [k][n]
    int tid = threadIdx.x;
    int row0 = blockIdx.x * 64, col0 = blockIdx.y * 64;
    int tx = tid & 15, ty = tid >> 4;
    float acc[4][4] = {};
    for (int k0 = 0; k0 < K; k0 += 16) {
#pragma unroll
        for (int i = 0; i < 4; i++) {
            int idx = tid + i * 256;
            int r = idx >> 4, kk = idx & 15;
            int gr = row0 + r;
            As[kk][r] = (gr < Mr) ? A[(size_t)gr * K + k0 + kk] : 0.0f;
            int k2 = idx >> 6, nn = idx & 63;
            Ws[k2][nn] = W[(size_t)(k0 + k2) * Nc + col0 + nn];
        }
        __syncthreads();
#pragma unroll
        for (int kk = 0; kk < 16; kk++) {
            float a[4], w[4];
#pragma unroll
            for (int i = 0; i < 4; i++) { a[i] = As[kk][ty * 4 + i]; w[i] = Ws[kk][tx * 4 + i]; }
#pragma unroll
            for (int i = 0; i < 4; i++)
#pragma unroll
                for (int j = 0; j < 4; j++) acc[i][j] += a[i] * w[j];
        }
        __syncthreads();
    }
#pragma unroll
    for (int i = 0; i < 4; i++) {
        int gr = row0 + ty * 4 + i;
        if (gr >= Mr) continue;
#pragma unroll
        for (int j = 0; j < 4; j++) {
            int gc = col0 + tx * 4 + j;
            float v = acc[i][j] + bias[gc];
            if (GELU) v = 0.5f * v * (1.0f + erff(v * 0.7071067811865475f));
            Co[(size_t)gr * Nc + gc] = v;
        }
    }
}

// ---------------- attention: o[b,h,n,m] = sigmoid(scale * q.k) ----------------
__global__ __launch_bounds__(256) void attn_kernel(
    const float* __restrict__ q, const float* __restrict__ k,
    float* __restrict__ o)
{
    // grid: b*(H*169) + h*169 + nt*13 + mt
    int mt = blockIdx.x % 13;
    int nt = (blockIdx.x / 13) % 13;
    int h  = (blockIdx.x / 169) % H_;
    int b  = blockIdx.x / (169 * H_);
    __shared__ float Qs[16][100];
    __shared__ float Ks[16][100];
    int tid = threadIdx.x;
    for (int idx = tid; idx < 16 * 96; idx += 256) {
        int r = idx / 96, c = idx % 96;
        int n = nt * 16 + r;
        Qs[r][c] = (n < N_) ? q[((size_t)(b * N_ + n)) * C_ + h * D_ + c] : 0.0f;
        int m = mt * 16 + r;
        Ks[r][c] = (m < M_) ? k[((size_t)(b * M_ + m)) * C_ + h * D_ + c] : 0.0f;
    }
    __syncthreads();
    int tm = tid & 15, tn = tid >> 4;
    float s = 0.f;
#pragma unroll 8
    for (int c = 0; c < 96; c++) s += Qs[tn][c] * Ks[tm][c];
    int n = nt * 16 + tn, m = mt * 16 + tm;
    if (n < N_ && m < M_) {
        const float scale = 0.10206207261596575f;  // 96^-0.5
        float z = s * scale;
        o[(((size_t)b * H_ + h) * N_ + n) * M_ + m] = 1.0f / (1.0f + expf(-z));
    }
}

// ---------------- c[b,m,h*D+d] = sum_n o[b,h,n,m] * cg[b,n,h*D+d] ----------------
__global__ __launch_bounds__(256) void pool_kernel(
    const float* __restrict__ o, const float* __restrict__ cg,
    float* __restrict__ cbuf)
{
    // grid: b*(H*78) + h*78 + mt*6 + dt   (13 m-tiles x 6 d-tiles)
    int dt = blockIdx.x % 6;
    int mt = (blockIdx.x / 6) % 13;
    int h  = (blockIdx.x / 78) % H_;
    int b  = blockIdx.x / (78 * H_);
    __shared__ float Os[16][17];
    __shared__ float Cs[16][17];
    int tid = threadIdx.x;
    int tm = tid & 15, td = tid >> 4;
    float acc = 0.f;
    for (int n0 = 0; n0 < N_; n0 += 16) {
        int n = n0 + (tid >> 4);
        int m = mt * 16 + (tid & 15);
        Os[tid >> 4][tid & 15] = (n < N_ && m < M_)
            ? o[(((size_t)b * H_ + h) * N_ + n) * M_ + m] : 0.0f;
        int dd = dt * 16 + (tid & 15);
        Cs[tid >> 4][tid & 15] = (n < N_)
            ? cg[((size_t)b * N_ + n) * C_ + h * D_ + dd] : 0.0f;
        __syncthreads();
#pragma unroll
        for (int nn = 0; nn < 16; nn++) acc += Os[nn][tm] * Cs[nn][td];
        __syncthreads();
    }
    int m = mt * 16 + tm, dd = dt * 16 + td;
    if (m < M_) cbuf[((size_t)b * M_ + m) * C_ + h * D_ + dd] = acc;
}

// ---------------- gate[b,h,m] = 1 - mean_n o[b,h,n,m] ----------------
__global__ __launch_bounds__(256) void gate_kernel(const float* __restrict__ o,
                                                   float* __restrict__ gate)
{
    int h = blockIdx.x % H_, b = blockIdx.x / H_;
    int m = threadIdx.x;
    if (m < M_) {
        const float* p = o + ((size_t)(b * H_ + h)) * N_ * M_ + m;
        float s = 0.f;
        for (int n = 0; n < N_; n++) s += p[(size_t)n * M_];
        gate[(b * H_ + h) * M_ + m] = 1.0f - s * (1.0f / N_);
    }
}

// ---------------- new_mem = LN(cnew + gate*memh) ----------------
__global__ __launch_bounds__(256) void final_kernel(
    const float* __restrict__ cnew, const float* __restrict__ gate,
    const float* __restrict__ memh,
    const float* __restrict__ w, const float* __restrict__ bia,
    float* __restrict__ mem)
{
    __shared__ float sdata[256];
    int row = blockIdx.x;          // b*M + m
    int b = row / M_, m = row % M_;
    float x[3];
    float sum = 0.f, sumsq = 0.f;
#pragma unroll
    for (int i = 0; i < 3; i++) {
        int c = threadIdx.x + i * 256;
        int h = c / D_;
        float v = cnew[(size_t)row * C_ + c] + gate[(b * H_ + h) * M_ + m] * memh[(size_t)row * C_ + c];
        x[i] = v;
        sum += v; sumsq += v * v;
    }
    sum = block_reduce_sum256(sum, sdata);
    sumsq = block_reduce_sum256(sumsq, sdata);
    float mu = sum * (1.0f / C_);
    float var = sumsq * (1.0f / C_) - mu * mu;
    float rs = rsqrtf(var + 1e-5f);
#pragma unroll
    for (int i = 0; i < 3; i++) {
        int c = threadIdx.x + i * 256;
        mem[(size_t)row * C_ + c] = (x[i] - mu) * rs * w[c] + bia[c];
    }
}

// ---------------- copy mem -> out (fp32) ----------------
__global__ __launch_bounds__(256) void out_kernel(const float* __restrict__ mem,
                                                  float* __restrict__ out, int n)
{
    int i = blockIdx.x * 256 + threadIdx.x;
    if (i < n) out[i] = mem[i];
}

extern "C" void kernel_launch(void* const* d_in, const int* in_sizes, int n_in,
                              void* d_out, int out_size, void* d_ws, size_t ws_size,
                              hipStream_t stream)
{
    const float* cur_fea = (const float*)d_in[0];
    const float* n1w = (const float*)d_in[1];
    const float* n1b = (const float*)d_in[2];
    const float* n2w = (const float*)d_in[3];
    const float* n2b = (const float*)d_in[4];
    const float* c_w1 = (const float*)d_in[5];
    const float* c_b1 = (const float*)d_in[6];
    const float* c_w2 = (const float*)d_in[7];
    const float* c_b2 = (const float*)d_in[8];
    const float* m_w1 = (const float*)d_in[9];
    const float* m_b1 = (const float*)d_in[10];
    const float* m_w2 = (const float*)d_in[11];
    const float* m_b2 = (const float*)d_in[12];
    const float* p_w1 = (const float*)d_in[13];
    const float* p_b1 = (const float*)d_in[14];
    const float* p_w2 = (const float*)d_in[15];
    const float* p_b2 = (const float*)d_in[16];
    const float* q_w = (const float*)d_in[17];
    const float* q_b = (const float*)d_in[18];
    const float* k_w = (const float*)d_in[19];
    const float* k_b = (const float*)d_in[20];

    // workspace carve-up (fp32), total ~72.5 MB
    float* ws = (float*)d_ws;
    float* mem  = ws;                   // 1204224
    float* cat  = mem  + 1204224;       // 2408448
    float* hid  = cat  + 2408448;       // 4816896
    float* cg   = hid  + 4816896;       // 1204224
    float* memh = cg   + 1204224;       // 1204224
    float* qb   = memh + 1204224;       // 1204224
    float* kb   = qb   + 1204224;       // 1204224
    float* ob   = kb   + 1204224;       // 2458624
    float* cbuf = ob   + 2458624;       // 1204224
    float* cnew = cbuf + 1204224;       // 1204224
    float* ap   = cnew + 1204224;       // 6144
    float* gate = ap   + 6144;          // 12544

    const dim3 blk(256);
    const dim3 gemm_big(25, 48);    // [1568 x 3072]
    const dim3 gemm_small(25, 12);  // [1568 x 768]

    // init memory = LN(frame 0)
    ln_frame_kernel<<<ROWS_, blk, 0, stream>>>(cur_fea, 0, n1w, n1b, mem);

    for (int t = 1; t < T_; t++) {
        ap_kernel<<<B_, 768, 0, stream>>>(mem, ap);
        build_cat_kernel<<<ROWS_, blk, 0, stream>>>(cur_fea, t, n1w, n1b, ap, cat);
        // c_func MLP
        gemm_kernel<1><<<gemm_big,   blk, 0, stream>>>(cat, c_w1, c_b1, hid, ROWS_, 2 * C_, HID_);
        gemm_kernel<0><<<gemm_small, blk, 0, stream>>>(hid, c_w2, c_b2, cg, ROWS_, HID_, C_);
        // m_func MLP
        gemm_kernel<1><<<gemm_big,   blk, 0, stream>>>(mem, m_w1, m_b1, hid, ROWS_, C_, HID_);
        gemm_kernel<0><<<gemm_small, blk, 0, stream>>>(hid, m_w2, m_b2, memh, ROWS_, HID_, C_);
        // q / k projections
        gemm_kernel<0><<<gemm_small, blk, 0, stream>>>(cg, q_w, q_b, qb, ROWS_, C_, C_);
        gemm_kernel<0><<<gemm_small, blk, 0, stream>>>(mem, k_w, k_b, kb, ROWS_, C_, C_);
        // sigmoid attention + pooling + gate
        attn_kernel<<<B_ * H_ * 13 * 13, blk, 0, stream>>>(qb, kb, ob);
        pool_kernel<<<B_ * H_ * 13 * 6, blk, 0, stream>>>(ob, cg, cbuf);
        gate_kernel<<<B_ * H_, blk, 0, stream>>>(ob, gate);
        // post MLP
        gemm_kernel<1><<<gemm_big,   blk, 0, stream>>>(cbuf, p_w1, p_b1, hid, ROWS_, C_, HID_);
        gemm_kernel<0><<<gemm_small, blk, 0, stream>>>(hid, p_w2, p_b2, cnew, ROWS_, HID_, C_);
        // residual gate + LN -> new mem (in place: only reads cnew/gate/memh)
        final_kernel<<<ROWS_, blk, 0, stream>>>(cnew, gate, memh, n2w, n2b, mem);
    }

    out_kernel<<<(B_ * M_ * C_ + 255) / 256, blk, 0, stream>>>(mem, (float*)d_out, B_ * M_ * C_);
}

// Round 3
// 5993.207 us; speedup vs baseline: 4.5231x; 4.5231x over previous
//
#include <hip/hip_runtime.h>
#include <hip/hip_bf16.h>
#include <math.h>

// Problem dims
constexpr int B_   = 8;
constexpr int T_   = 16;
constexpr int N_   = 196;
constexpr int C_   = 768;
constexpr int H_   = 8;
constexpr int D_   = 96;
constexpr int M_   = 196;    // MEM
constexpr int HID_ = 3072;
constexpr int ROWS_ = B_ * N_;   // 1568 == B_*M_
constexpr int MP_   = 1664;      // ROWS_ padded to multiple of 128 (13*128)

typedef __hip_bfloat16 bf16;
typedef __attribute__((ext_vector_type(8))) short bf16x8;
typedef __attribute__((ext_vector_type(4))) float f32x4;

__device__ __forceinline__ float b2f(bf16 x) { return __bfloat162float(x); }

#define GL2LDS(g, l) __builtin_amdgcn_global_load_lds( \
    (__attribute__((address_space(1))) void*)(g), \
    (__attribute__((address_space(3))) void*)(l), 16, 0, 0)

// ---------------- block reduction (256 threads) ----------------
__device__ __forceinline__ float block_reduce_sum256(float v, float* sdata) {
    int tid = threadIdx.x;
    sdata[tid] = v;
    __syncthreads();
    for (int s = 128; s > 0; s >>= 1) {
        if (tid < s) sdata[tid] += sdata[tid + s];
        __syncthreads();
    }
    float r = sdata[0];
    __syncthreads();
    return r;
}

// ---------------- weight convert + transpose: W[K,N] fp32 -> Wt[N,K] bf16 ----------------
__global__ __launch_bounds__(256) void transpose_cvt_kernel(
    const float* __restrict__ W, bf16* __restrict__ Wt, int K, int N)
{
    __shared__ float tile[32][33];
    int tx = threadIdx.x & 31, ty = threadIdx.x >> 5;   // 8 rows per pass
    int n0 = blockIdx.x * 32, k0 = blockIdx.y * 32;
#pragma unroll
    for (int i = 0; i < 32; i += 8)
        tile[ty + i][tx] = W[(size_t)(k0 + ty + i) * N + n0 + tx];
    __syncthreads();
#pragma unroll
    for (int i = 0; i < 32; i += 8)
        Wt[(size_t)(n0 + ty + i) * K + k0 + tx] = __float2bfloat16(tile[tx][ty + i]);
}

// ---------------- LN of frame 0 -> mem (fp32) + mem_bf (bf16) ----------------
__global__ __launch_bounds__(256) void ln_frame_kernel(
    const float* __restrict__ cur, int t,
    const float* __restrict__ w, const float* __restrict__ bia,
    float* __restrict__ mem, bf16* __restrict__ mem_bf)
{
    __shared__ float sdata[256];
    int row = blockIdx.x;              // b*N + n
    int b = row / N_, n = row % N_;
    const float* src = cur + (((size_t)b * T_ + t) * N_ + n) * C_;
    float x[3];
    float sum = 0.f, sumsq = 0.f;
#pragma unroll
    for (int i = 0; i < 3; i++) {
        int c = threadIdx.x + i * 256;
        x[i] = src[c];
        sum += x[i]; sumsq += x[i] * x[i];
    }
    sum = block_reduce_sum256(sum, sdata);
    sumsq = block_reduce_sum256(sumsq, sdata);
    float mu = sum * (1.0f / C_);
    float var = sumsq * (1.0f / C_) - mu * mu;
    float rs = rsqrtf(var + 1e-5f);
#pragma unroll
    for (int i = 0; i < 3; i++) {
        int c = threadIdx.x + i * 256;
        float v = (x[i] - mu) * rs * w[c] + bia[c];
        mem[(size_t)row * C_ + c] = v;
        mem_bf[(size_t)row * C_ + c] = __float2bfloat16(v);
    }
}

// ---------------- ap[b,c] = mean_m mem[b,m,c] ----------------
__global__ __launch_bounds__(768) void ap_kernel(const float* __restrict__ mem,
                                                 float* __restrict__ ap)
{
    int b = blockIdx.x;
    int c = threadIdx.x;   // 768 threads
    const float* p = mem + (size_t)b * M_ * C_ + c;
    float s = 0.f;
    for (int m = 0; m < M_; m++) s += p[(size_t)m * C_];
    ap[b * C_ + c] = s * (1.0f / M_);
}

// ---------------- cat[row,0:C]=LN(frame t), cat[row,C:2C]=ap[b]  (bf16) ----------------
__global__ __launch_bounds__(256) void build_cat_kernel(
    const float* __restrict__ cur, int t,
    const float* __restrict__ w, const float* __restrict__ bia,
    const float* __restrict__ ap, bf16* __restrict__ cat)
{
    __shared__ float sdata[256];
    int row = blockIdx.x;
    int b = row / N_, n = row % N_;
    const float* src = cur + (((size_t)b * T_ + t) * N_ + n) * C_;
    float x[3];
    float sum = 0.f, sumsq = 0.f;
#pragma unroll
    for (int i = 0; i < 3; i++) {
        int c = threadIdx.x + i * 256;
        x[i] = src[c];
        sum += x[i]; sumsq += x[i] * x[i];
    }
    sum = block_reduce_sum256(sum, sdata);
    sumsq = block_reduce_sum256(sumsq, sdata);
    float mu = sum * (1.0f / C_);
    float var = sumsq * (1.0f / C_) - mu * mu;
    float rs = rsqrtf(var + 1e-5f);
    bf16* dstrow = cat + (size_t)row * (2 * C_);
#pragma unroll
    for (int i = 0; i < 3; i++) {
        int c = threadIdx.x + i * 256;
        dstrow[c] = __float2bfloat16((x[i] - mu) * rs * w[c] + bia[c]);
        dstrow[C_ + c] = __float2bfloat16(ap[b * C_ + c]);
    }
}

// ---------------- MFMA GEMM: out[Mp,N](bf16) = A[Mp,K](bf16) x Wt[N,K](bf16)^T + bias ----------------
// BM=128, BK=32, BN template (128 or 64). 256 threads = 4 waves in 2x2.
// No bounds checks: Mp % 128 == 0, N % BN == 0, K % 32 == 0.
template <int BN, int GELU>
__global__ __launch_bounds__(256) void mfma_gemm(
    const bf16* __restrict__ A, const bf16* __restrict__ Wt,
    const float* __restrict__ bias, bf16* __restrict__ out,
    int K, int N)
{
    constexpr int BM = 128;
    constexpr int BK = 32;
    constexpr int TI = 4;            // 64/16 rows of mfma tiles per wave
    constexpr int TJ = (BN / 2) / 16; // 4 (BN=128) or 2 (BN=64)
    __shared__ short As[BM * BK];    // [m][k], k contiguous (64 B/row)
    __shared__ short Bs[BN * BK];    // [n][k]

    int tid = threadIdx.x;
    int wid = tid >> 6;
    int lane = tid & 63;
    int quad = lane >> 4, l15 = lane & 15;
    int row0 = blockIdx.x * BM;
    int col0 = blockIdx.y * BN;
    int wm = (wid >> 1) * 64;        // wave row offset in tile
    int wn = (wid & 1) * (BN / 2);   // wave col offset in tile

    f32x4 acc[TI][TJ] = {};

    const char* Ab = (const char*)A;
    const char* Wb = (const char*)Wt;
    const size_t Kb = (size_t)K * 2; // row stride bytes

    for (int k0 = 0; k0 < K; k0 += BK) {
        // ---- stage A tile: BM*64 bytes; 4KB per round (4 waves x 1KB) ----
        {
            int base = wid * 1024;
#pragma unroll
            for (int r = 0; r < (BM * 64) / 4096; r++) {
                int byteidx = base + r * 4096 + lane * 16;
                int row = byteidx >> 6, kbyte = byteidx & 63;
                GL2LDS(Ab + (size_t)(row0 + row) * Kb + (size_t)k0 * 2 + kbyte,
                       (char*)As + base + r * 4096);
            }
#pragma unroll
            for (int r = 0; r < (BN * 64) / 4096; r++) {
                int byteidx = base + r * 4096 + lane * 16;
                int n = byteidx >> 6, kbyte = byteidx & 63;
                GL2LDS(Wb + (size_t)(col0 + n) * Kb + (size_t)k0 * 2 + kbyte,
                       (char*)Bs + base + r * 4096);
            }
        }
        __syncthreads();
        // ---- compute ----
        const bf16x8* Av = (const bf16x8*)As;
        const bf16x8* Bv = (const bf16x8*)Bs;
        bf16x8 af[TI], bfr[TJ];
#pragma unroll
        for (int i = 0; i < TI; i++)
            af[i] = Av[(wm + i * 16 + l15) * (BK / 8) + quad];
#pragma unroll
        for (int j = 0; j < TJ; j++)
            bfr[j] = Bv[(wn + j * 16 + l15) * (BK / 8) + quad];
#pragma unroll
        for (int i = 0; i < TI; i++)
#pragma unroll
            for (int j = 0; j < TJ; j++)
                acc[i][j] = __builtin_amdgcn_mfma_f32_16x16x32_bf16(
                    af[i], bfr[j], acc[i][j], 0, 0, 0);
        __syncthreads();
    }

    // ---- epilogue: C/D layout col=lane&15, row=quad*4+reg ----
#pragma unroll
    for (int i = 0; i < TI; i++) {
        int gr = row0 + wm + i * 16 + quad * 4;
#pragma unroll
        for (int j = 0; j < TJ; j++) {
            int gc = col0 + wn + j * 16 + l15;
            float bv = bias[gc];
#pragma unroll
            for (int r = 0; r < 4; r++) {
                float v = acc[i][j][r] + bv;
                if (GELU) v = 0.5f * v * (1.0f + erff(v * 0.7071067811865475f));
                out[(size_t)(gr + r) * N + gc] = __float2bfloat16(v);
            }
        }
    }
}

// ---------------- attention: o[b,h,n,m] = sigmoid(scale * q.k)  (q,k bf16) ----------------
__global__ __launch_bounds__(256) void attn_kernel(
    const bf16* __restrict__ q, const bf16* __restrict__ k,
    float* __restrict__ o)
{
    int mt = blockIdx.x % 13;
    int nt = (blockIdx.x / 13) % 13;
    int h  = (blockIdx.x / 169) % H_;
    int b  = blockIdx.x / (169 * H_);
    __shared__ float Qs[16][100];
    __shared__ float Ks[16][100];
    int tid = threadIdx.x;
    for (int idx = tid; idx < 16 * 96; idx += 256) {
        int r = idx / 96, c = idx % 96;
        int n = nt * 16 + r;
        Qs[r][c] = (n < N_) ? b2f(q[((size_t)(b * N_ + n)) * C_ + h * D_ + c]) : 0.0f;
        int m = mt * 16 + r;
        Ks[r][c] = (m < M_) ? b2f(k[((size_t)(b * M_ + m)) * C_ + h * D_ + c]) : 0.0f;
    }
    __syncthreads();
    int tm = tid & 15, tn = tid >> 4;
    float s = 0.f;
#pragma unroll 8
    for (int c = 0; c < 96; c++) s += Qs[tn][c] * Ks[tm][c];
    int n = nt * 16 + tn, m = mt * 16 + tm;
    if (n < N_ && m < M_) {
        const float scale = 0.10206207261596575f;  // 96^-0.5
        float z = s * scale;
        o[(((size_t)b * H_ + h) * N_ + n) * M_ + m] = 1.0f / (1.0f + expf(-z));
    }
}

// ---------------- cbuf[b,m,h*D+d] = sum_n o[b,h,n,m] * cg[b,n,h*D+d]  (bf16 out) ----------------
__global__ __launch_bounds__(256) void pool_kernel(
    const float* __restrict__ o, const bf16* __restrict__ cg,
    bf16* __restrict__ cbuf)
{
    int dt = blockIdx.x % 6;
    int mt = (blockIdx.x / 6) % 13;
    int h  = (blockIdx.x / 78) % H_;
    int b  = blockIdx.x / (78 * H_);
    __shared__ float Os[16][17];
    __shared__ float Cs[16][17];
    int tid = threadIdx.x;
    int tm = tid & 15, td = tid >> 4;
    float acc = 0.f;
    for (int n0 = 0; n0 < N_; n0 += 16) {
        int n = n0 + (tid >> 4);
        int m = mt * 16 + (tid & 15);
        Os[tid >> 4][tid & 15] = (n < N_ && m < M_)
            ? o[(((size_t)b * H_ + h) * N_ + n) * M_ + m] : 0.0f;
        int dd = dt * 16 + (tid & 15);
        Cs[tid >> 4][tid & 15] = (n < N_)
            ? b2f(cg[((size_t)b * N_ + n) * C_ + h * D_ + dd]) : 0.0f;
        __syncthreads();
#pragma unroll
        for (int nn = 0; nn < 16; nn++) acc += Os[nn][tm] * Cs[nn][td];
        __syncthreads();
    }
    int m = mt * 16 + tm, dd = dt * 16 + td;
    if (m < M_) cbuf[((size_t)b * M_ + m) * C_ + h * D_ + dd] = __float2bfloat16(acc);
}

// ---------------- gate[b,h,m] = 1 - mean_n o[b,h,n,m] ----------------
__global__ __launch_bounds__(256) void gate_kernel(const float* __restrict__ o,
                                                   float* __restrict__ gate)
{
    int h = blockIdx.x % H_, b = blockIdx.x / H_;
    int m = threadIdx.x;
    if (m < M_) {
        const float* p = o + ((size_t)(b * H_ + h)) * N_ * M_ + m;
        float s = 0.f;
        for (int n = 0; n < N_; n++) s += p[(size_t)n * M_];
        gate[(b * H_ + h) * M_ + m] = 1.0f - s * (1.0f / N_);
    }
}

// ---------------- new_mem = LN(cnew + gate*memh) -> mem fp32 + mem_bf bf16 ----------------
__global__ __launch_bounds__(256) void final_kernel(
    const bf16* __restrict__ cnew, const float* __restrict__ gate,
    const bf16* __restrict__ memh,
    const float* __restrict__ w, const float* __restrict__ bia,
    float* __restrict__ mem, bf16* __restrict__ mem_bf)
{
    __shared__ float sdata[256];
    int row = blockIdx.x;          // b*M + m
    int b = row / M_, m = row % M_;
    float x[3];
    float sum = 0.f, sumsq = 0.f;
#pragma unroll
    for (int i = 0; i < 3; i++) {
        int c = threadIdx.x + i * 256;
        int h = c / D_;
        float v = b2f(cnew[(size_t)row * C_ + c])
                + gate[(b * H_ + h) * M_ + m] * b2f(memh[(size_t)row * C_ + c]);
        x[i] = v;
        sum += v; sumsq += v * v;
    }
    sum = block_reduce_sum256(sum, sdata);
    sumsq = block_reduce_sum256(sumsq, sdata);
    float mu = sum * (1.0f / C_);
    float var = sumsq * (1.0f / C_) - mu * mu;
    float rs = rsqrtf(var + 1e-5f);
#pragma unroll
    for (int i = 0; i < 3; i++) {
        int c = threadIdx.x + i * 256;
        float v = (x[i] - mu) * rs * w[c] + bia[c];
        mem[(size_t)row * C_ + c] = v;
        mem_bf[(size_t)row * C_ + c] = __float2bfloat16(v);
    }
}

// ---------------- copy mem -> out (fp32) ----------------
__global__ __launch_bounds__(256) void out_kernel(const float* __restrict__ mem,
                                                  float* __restrict__ out, int n)
{
    int i = blockIdx.x * 256 + threadIdx.x;
    if (i < n) out[i] = mem[i];
}

extern "C" void kernel_launch(void* const* d_in, const int* in_sizes, int n_in,
                              void* d_out, int out_size, void* d_ws, size_t ws_size,
                              hipStream_t stream)
{
    const float* cur_fea = (const float*)d_in[0];
    const float* n1w = (const float*)d_in[1];
    const float* n1b = (const float*)d_in[2];
    const float* n2w = (const float*)d_in[3];
    const float* n2b = (const float*)d_in[4];
    const float* c_w1 = (const float*)d_in[5];
    const float* c_b1 = (const float*)d_in[6];
    const float* c_w2 = (const float*)d_in[7];
    const float* c_b2 = (const float*)d_in[8];
    const float* m_w1 = (const float*)d_in[9];
    const float* m_b1 = (const float*)d_in[10];
    const float* m_w2 = (const float*)d_in[11];
    const float* m_b2 = (const float*)d_in[12];
    const float* p_w1 = (const float*)d_in[13];
    const float* p_b1 = (const float*)d_in[14];
    const float* p_w2 = (const float*)d_in[15];
    const float* p_b2 = (const float*)d_in[16];
    const float* q_w = (const float*)d_in[17];
    const float* q_b = (const float*)d_in[18];
    const float* k_w = (const float*)d_in[19];
    const float* k_b = (const float*)d_in[20];

    // ---- workspace carve (256B-aligned), total ~68.7 MB ----
    size_t off = 0;
    char* base = (char*)d_ws;
    auto carve = [&](size_t bytes) -> char* {
        char* r = base + off;
        off += (bytes + 255) & ~(size_t)255;
        return r;
    };
    bf16* cw1t = (bf16*)carve((size_t)HID_ * (2 * C_) * 2);   // [3072,1536]
    bf16* cw2t = (bf16*)carve((size_t)C_ * HID_ * 2);         // [768,3072]
    bf16* mw1t = (bf16*)carve((size_t)HID_ * C_ * 2);         // [3072,768]
    bf16* mw2t = (bf16*)carve((size_t)C_ * HID_ * 2);
    bf16* pw1t = (bf16*)carve((size_t)HID_ * C_ * 2);
    bf16* pw2t = (bf16*)carve((size_t)C_ * HID_ * 2);
    bf16* qwt  = (bf16*)carve((size_t)C_ * C_ * 2);
    bf16* kwt  = (bf16*)carve((size_t)C_ * C_ * 2);
    float* mem   = (float*)carve((size_t)MP_ * C_ * 4);
    bf16*  mem_bf = (bf16*)carve((size_t)MP_ * C_ * 2);
    char* catreg = carve((size_t)MP_ * 2 * C_ * 2);           // cat; later qb|kb
    bf16* cat = (bf16*)catreg;
    bf16* qb  = (bf16*)catreg;                                // alias (cat dead after c1)
    bf16* kb  = (bf16*)catreg + (size_t)MP_ * C_;
    char* hidreg = carve((size_t)MP_ * HID_ * 2);             // hid; later ob (9.83MB<10.22MB)
    bf16*  hid = (bf16*)hidreg;
    float* ob  = (float*)hidreg;                              // alias (hid dead m2->p1)
    bf16* cg    = (bf16*)carve((size_t)MP_ * C_ * 2);
    bf16* cbuf  = (bf16*)carve((size_t)MP_ * C_ * 2);
    bf16* memh  = (bf16*)carve((size_t)MP_ * C_ * 2);
    bf16* cnew  = (bf16*)carve((size_t)MP_ * C_ * 2);
    float* ap   = (float*)carve((size_t)B_ * C_ * 4);
    float* gateb = (float*)carve((size_t)B_ * H_ * M_ * 4);

    const dim3 blk(256);
    const dim3 gbig(MP_ / 128, HID_ / 128);   // (13,24)
    const dim3 gsml(MP_ / 128, C_ / 64);      // (13,12)

    // ---- weight convert + transpose (once per call) ----
    transpose_cvt_kernel<<<dim3(HID_ / 32, (2 * C_) / 32), blk, 0, stream>>>(c_w1, cw1t, 2 * C_, HID_);
    transpose_cvt_kernel<<<dim3(C_ / 32, HID_ / 32), blk, 0, stream>>>(c_w2, cw2t, HID_, C_);
    transpose_cvt_kernel<<<dim3(HID_ / 32, C_ / 32), blk, 0, stream>>>(m_w1, mw1t, C_, HID_);
    transpose_cvt_kernel<<<dim3(C_ / 32, HID_ / 32), blk, 0, stream>>>(m_w2, mw2t, HID_, C_);
    transpose_cvt_kernel<<<dim3(HID_ / 32, C_ / 32), blk, 0, stream>>>(p_w1, pw1t, C_, HID_);
    transpose_cvt_kernel<<<dim3(C_ / 32, HID_ / 32), blk, 0, stream>>>(p_w2, pw2t, HID_, C_);
    transpose_cvt_kernel<<<dim3(C_ / 32, C_ / 32), blk, 0, stream>>>(q_w, qwt, C_, C_);
    transpose_cvt_kernel<<<dim3(C_ / 32, C_ / 32), blk, 0, stream>>>(k_w, kwt, C_, C_);

    // ---- init memory = LN(frame 0) ----
    ln_frame_kernel<<<ROWS_, blk, 0, stream>>>(cur_fea, 0, n1w, n1b, mem, mem_bf);

    for (int t = 1; t < T_; t++) {
        ap_kernel<<<B_, 768, 0, stream>>>(mem, ap);
        build_cat_kernel<<<ROWS_, blk, 0, stream>>>(cur_fea, t, n1w, n1b, ap, cat);
        // c_func MLP
        mfma_gemm<128, 1><<<gbig, blk, 0, stream>>>(cat, cw1t, c_b1, hid, 2 * C_, HID_);
        mfma_gemm<64, 0><<<gsml, blk, 0, stream>>>(hid, cw2t, c_b2, cg, HID_, C_);
        // m_func MLP
        mfma_gemm<128, 1><<<gbig, blk, 0, stream>>>(mem_bf, mw1t, m_b1, hid, C_, HID_);
        mfma_gemm<64, 0><<<gsml, blk, 0, stream>>>(hid, mw2t, m_b2, memh, HID_, C_);
        // q / k projections (qb/kb alias cat region — cat consumed by c1 above)
        mfma_gemm<64, 0><<<gsml, blk, 0, stream>>>(cg, qwt, q_b, qb, C_, C_);
        mfma_gemm<64, 0><<<gsml, blk, 0, stream>>>(mem_bf, kwt, k_b, kb, C_, C_);
        // sigmoid attention + pooling + gate (ob aliases hid — hid dead until p1)
        attn_kernel<<<B_ * H_ * 13 * 13, blk, 0, stream>>>(qb, kb, ob);
        pool_kernel<<<B_ * H_ * 13 * 6, blk, 0, stream>>>(ob, cg, cbuf);
        gate_kernel<<<B_ * H_, blk, 0, stream>>>(ob, gateb);
        // post MLP (p1 overwrites ob region — ob consumed above)
        mfma_gemm<128, 1><<<gbig, blk, 0, stream>>>(cbuf, pw1t, p_b1, hid, C_, HID_);
        mfma_gemm<64, 0><<<gsml, blk, 0, stream>>>(hid, pw2t, p_b2, cnew, HID_, C_);
        // residual gate + LN -> new mem
        final_kernel<<<ROWS_, blk, 0, stream>>>(cnew, gateb, memh, n2w, n2b, mem, mem_bf);
    }

    out_kernel<<<(B_ * M_ * C_ + 255) / 256, blk, 0, stream>>>(mem, (float*)d_out, B_ * M_ * C_);
}

// Round 5
// 4703.363 us; speedup vs baseline: 5.7635x; 1.2742x over previous
//
#include <hip/hip_runtime.h>
#include <hip/hip_bf16.h>
#include <math.h>

// Problem dims
constexpr int B_   = 8;
constexpr int T_   = 16;
constexpr int N_   = 196;
constexpr int C_   = 768;
constexpr int H_   = 8;
constexpr int D_   = 96;
constexpr int M_   = 196;    // MEM
constexpr int HID_ = 3072;
constexpr int ROWS_ = B_ * N_;   // 1568 == B_*M_
constexpr int MP_   = 1664;      // ROWS_ padded to multiple of 128 (13*128)

typedef __hip_bfloat16 bf16;
typedef __attribute__((ext_vector_type(8))) short bf16x8;
typedef __attribute__((ext_vector_type(4))) float f32x4;

__device__ __forceinline__ float b2f(bf16 x) { return __bfloat162float(x); }

#define GL2LDS(g, l) __builtin_amdgcn_global_load_lds( \
    (__attribute__((address_space(1))) void*)(g), \
    (__attribute__((address_space(3))) void*)(l), 16, 0, 0)

// ---------------- block reduction (256 threads) ----------------
__device__ __forceinline__ float block_reduce_sum256(float v, float* sdata) {
    int tid = threadIdx.x;
    sdata[tid] = v;
    __syncthreads();
    for (int s = 128; s > 0; s >>= 1) {
        if (tid < s) sdata[tid] += sdata[tid + s];
        __syncthreads();
    }
    float r = sdata[0];
    __syncthreads();
    return r;
}

// ---------------- weight convert + transpose: W[K,N] fp32 -> Wt[N,K] bf16 ----------------
__global__ __launch_bounds__(256) void transpose_cvt_kernel(
    const float* __restrict__ W, bf16* __restrict__ Wt, int K, int N)
{
    __shared__ float tile[32][33];
    int tx = threadIdx.x & 31, ty = threadIdx.x >> 5;   // 8 rows per pass
    int n0 = blockIdx.x * 32, k0 = blockIdx.y * 32;
#pragma unroll
    for (int i = 0; i < 32; i += 8)
        tile[ty + i][tx] = W[(size_t)(k0 + ty + i) * N + n0 + tx];
    __syncthreads();
#pragma unroll
    for (int i = 0; i < 32; i += 8)
        Wt[(size_t)(n0 + ty + i) * K + k0 + tx] = __float2bfloat16(tile[tx][ty + i]);
}

// ---------------- LN of frame 0 -> mem_bf (bf16) ----------------
__global__ __launch_bounds__(256) void ln_frame_kernel(
    const float* __restrict__ cur, int t,
    const float* __restrict__ w, const float* __restrict__ bia,
    bf16* __restrict__ mem_bf)
{
    __shared__ float sdata[256];
    int row = blockIdx.x;              // b*N + n
    int b = row / N_, n = row % N_;
    const float* src = cur + (((size_t)b * T_ + t) * N_ + n) * C_;
    float x[3];
    float sum = 0.f, sumsq = 0.f;
#pragma unroll
    for (int i = 0; i < 3; i++) {
        int c = threadIdx.x + i * 256;
        x[i] = src[c];
        sum += x[i]; sumsq += x[i] * x[i];
    }
    sum = block_reduce_sum256(sum, sdata);
    sumsq = block_reduce_sum256(sumsq, sdata);
    float mu = sum * (1.0f / C_);
    float var = sumsq * (1.0f / C_) - mu * mu;
    float rs = rsqrtf(var + 1e-5f);
#pragma unroll
    for (int i = 0; i < 3; i++) {
        int c = threadIdx.x + i * 256;
        mem_bf[(size_t)row * C_ + c] = __float2bfloat16((x[i] - mu) * rs * w[c] + bia[c]);
    }
}

// ---------------- ap[b,c] = mean_m mem[b,m,c] (bf16 in, fp32 out) ----------------
__global__ __launch_bounds__(768) void ap_kernel(const bf16* __restrict__ mem,
                                                 float* __restrict__ ap)
{
    int b = blockIdx.x;
    int c = threadIdx.x;   // 768 threads
    const bf16* p = mem + (size_t)b * M_ * C_ + c;
    float s = 0.f;
    for (int m = 0; m < M_; m++) s += b2f(p[(size_t)m * C_]);
    ap[b * C_ + c] = s * (1.0f / M_);
}

// ---------------- cat[row,0:C]=LN(frame t), cat[row,C:2C]=ap[b]  (bf16) ----------------
__global__ __launch_bounds__(256) void build_cat_kernel(
    const float* __restrict__ cur, int t,
    const float* __restrict__ w, const float* __restrict__ bia,
    const float* __restrict__ ap, bf16* __restrict__ cat)
{
    __shared__ float sdata[256];
    int row = blockIdx.x;
    int b = row / N_, n = row % N_;
    const float* src = cur + (((size_t)b * T_ + t) * N_ + n) * C_;
    float x[3];
    float sum = 0.f, sumsq = 0.f;
#pragma unroll
    for (int i = 0; i < 3; i++) {
        int c = threadIdx.x + i * 256;
        x[i] = src[c];
        sum += x[i]; sumsq += x[i] * x[i];
    }
    sum = block_reduce_sum256(sum, sdata);
    sumsq = block_reduce_sum256(sumsq, sdata);
    float mu = sum * (1.0f / C_);
    float var = sumsq * (1.0f / C_) - mu * mu;
    float rs = rsqrtf(var + 1e-5f);
    bf16* dstrow = cat + (size_t)row * (2 * C_);
#pragma unroll
    for (int i = 0; i < 3; i++) {
        int c = threadIdx.x + i * 256;
        dstrow[c] = __float2bfloat16((x[i] - mu) * rs * w[c] + bia[c]);
        dstrow[C_ + c] = __float2bfloat16(ap[b * C_ + c]);
    }
}

// ---------------- batched MFMA GEMM (up to 3 sub-problems via blockIdx.z) ----------------
// out[MP_,N](bf16) = A[MP_,K](bf16) x Wt[N,K]^T + bias ; optional GELU.
// BM=128, BK=32, BN template. 256 threads = 4 waves (2x2).
struct GemmDesc {
    const bf16* A; const bf16* W; const float* bias; bf16* out;
    int K; int N; int ymax; int gelu;
};
struct GemmDescs { GemmDesc d[3]; };

template <int BN>
__global__ __launch_bounds__(256) void mfma_gemm_multi(GemmDescs ds)
{
    constexpr int BM = 128;
    constexpr int BK = 32;
    constexpr int TI = 4;
    constexpr int TJ = (BN / 2) / 16;
    __shared__ short As[BM * BK];
    __shared__ short Bs[BN * BK];

    GemmDesc g = ds.d[blockIdx.z];
    if ((int)blockIdx.y >= g.ymax) return;

    int tid = threadIdx.x;
    int wid = tid >> 6;
    int lane = tid & 63;
    int quad = lane >> 4, l15 = lane & 15;
    int row0 = blockIdx.x * BM;
    int col0 = blockIdx.y * BN;
    int wm = (wid >> 1) * 64;
    int wn = (wid & 1) * (BN / 2);

    f32x4 acc[TI][TJ] = {};

    const char* Ab = (const char*)g.A;
    const char* Wb = (const char*)g.W;
    const size_t Kb = (size_t)g.K * 2;

    for (int k0 = 0; k0 < g.K; k0 += BK) {
        int base = wid * 1024;
#pragma unroll
        for (int r = 0; r < (BM * 64) / 4096; r++) {
            int byteidx = base + r * 4096 + lane * 16;
            int row = byteidx >> 6, kbyte = byteidx & 63;
            GL2LDS(Ab + (size_t)(row0 + row) * Kb + (size_t)k0 * 2 + kbyte,
                   (char*)As + base + r * 4096);
        }
#pragma unroll
        for (int r = 0; r < (BN * 64) / 4096; r++) {
            int byteidx = base + r * 4096 + lane * 16;
            int n = byteidx >> 6, kbyte = byteidx & 63;
            GL2LDS(Wb + (size_t)(col0 + n) * Kb + (size_t)k0 * 2 + kbyte,
                   (char*)Bs + base + r * 4096);
        }
        __syncthreads();
        const bf16x8* Av = (const bf16x8*)As;
        const bf16x8* Bv = (const bf16x8*)Bs;
        bf16x8 af[TI], bfr[TJ];
#pragma unroll
        for (int i = 0; i < TI; i++)
            af[i] = Av[(wm + i * 16 + l15) * (BK / 8) + quad];
#pragma unroll
        for (int j = 0; j < TJ; j++)
            bfr[j] = Bv[(wn + j * 16 + l15) * (BK / 8) + quad];
#pragma unroll
        for (int i = 0; i < TI; i++)
#pragma unroll
            for (int j = 0; j < TJ; j++)
                acc[i][j] = __builtin_amdgcn_mfma_f32_16x16x32_bf16(
                    af[i], bfr[j], acc[i][j], 0, 0, 0);
        __syncthreads();
    }

    // epilogue: C/D layout col=lane&15, row=quad*4+reg
#pragma unroll
    for (int i = 0; i < TI; i++) {
        int gr = row0 + wm + i * 16 + quad * 4;
#pragma unroll
        for (int j = 0; j < TJ; j++) {
            int gc = col0 + wn + j * 16 + l15;
            float bv = g.bias[gc];
#pragma unroll
            for (int r = 0; r < 4; r++) {
                float v = acc[i][j][r] + bv;
                if (g.gelu) v = 0.5f * v * (1.0f + erff(v * 0.7071067811865475f));
                g.out[(size_t)(gr + r) * g.N + gc] = __float2bfloat16(v);
            }
        }
    }
}

// ---------------- split-K MFMA GEMM for p2: part[z][MP_,768] fp32, no bias ----------------
__global__ __launch_bounds__(256) void mfma_gemm_splitk(
    const bf16* __restrict__ A, const bf16* __restrict__ Wt,
    float* __restrict__ part, int K)
{
    constexpr int BM = 128;
    constexpr int BN = 64;
    constexpr int BK = 32;
    constexpr int TI = 4;
    constexpr int TJ = 2;
    __shared__ short As[BM * BK];
    __shared__ short Bs[BN * BK];

    int tid = threadIdx.x;
    int wid = tid >> 6;
    int lane = tid & 63;
    int quad = lane >> 4, l15 = lane & 15;
    int row0 = blockIdx.x * BM;
    int col0 = blockIdx.y * BN;
    int wm = (wid >> 1) * 64;
    int wn = (wid & 1) * (BN / 2);
    int kh = K >> 1;
    int kbeg = blockIdx.z * kh, kend = kbeg + kh;

    f32x4 acc[TI][TJ] = {};
    const char* Ab = (const char*)A;
    const char* Wb = (const char*)Wt;
    const size_t Kb = (size_t)K * 2;

    for (int k0 = kbeg; k0 < kend; k0 += BK) {
        int base = wid * 1024;
#pragma unroll
        for (int r = 0; r < (BM * 64) / 4096; r++) {
            int byteidx = base + r * 4096 + lane * 16;
            int row = byteidx >> 6, kbyte = byteidx & 63;
            GL2LDS(Ab + (size_t)(row0 + row) * Kb + (size_t)k0 * 2 + kbyte,
                   (char*)As + base + r * 4096);
        }
#pragma unroll
        for (int r = 0; r < (BN * 64) / 4096; r++) {
            int byteidx = base + r * 4096 + lane * 16;
            int n = byteidx >> 6, kbyte = byteidx & 63;
            GL2LDS(Wb + (size_t)(col0 + n) * Kb + (size_t)k0 * 2 + kbyte,
                   (char*)Bs + base + r * 4096);
        }
        __syncthreads();
        const bf16x8* Av = (const bf16x8*)As;
        const bf16x8* Bv = (const bf16x8*)Bs;
        bf16x8 af[TI], bfr[TJ];
#pragma unroll
        for (int i = 0; i < TI; i++)
            af[i] = Av[(wm + i * 16 + l15) * (BK / 8) + quad];
#pragma unroll
        for (int j = 0; j < TJ; j++)
            bfr[j] = Bv[(wn + j * 16 + l15) * (BK / 8) + quad];
#pragma unroll
        for (int i = 0; i < TI; i++)
#pragma unroll
            for (int j = 0; j < TJ; j++)
                acc[i][j] = __builtin_amdgcn_mfma_f32_16x16x32_bf16(
                    af[i], bfr[j], acc[i][j], 0, 0, 0);
        __syncthreads();
    }

    float* outp = part + (size_t)blockIdx.z * MP_ * C_;
#pragma unroll
    for (int i = 0; i < TI; i++) {
        int gr = row0 + wm + i * 16 + quad * 4;
#pragma unroll
        for (int j = 0; j < TJ; j++) {
            int gc = col0 + wn + j * 16 + l15;
#pragma unroll
            for (int r = 0; r < 4; r++)
                outp[(size_t)(gr + r) * C_ + gc] = acc[i][j][r];
        }
    }
}

// ---------------- attention: o[b,h,n,m] = sigmoid(scale * q.k)  (q,k bf16) ----------------
__global__ __launch_bounds__(256) void attn_kernel(
    const bf16* __restrict__ q, const bf16* __restrict__ k,
    float* __restrict__ o)
{
    int mt = blockIdx.x % 13;
    int nt = (blockIdx.x / 13) % 13;
    int h  = (blockIdx.x / 169) % H_;
    int b  = blockIdx.x / (169 * H_);
    __shared__ float Qs[16][100];
    __shared__ float Ks[16][100];
    int tid = threadIdx.x;
    for (int idx = tid; idx < 16 * 96; idx += 256) {
        int r = idx / 96, c = idx % 96;
        int n = nt * 16 + r;
        Qs[r][c] = (n < N_) ? b2f(q[((size_t)(b * N_ + n)) * C_ + h * D_ + c]) : 0.0f;
        int m = mt * 16 + r;
        Ks[r][c] = (m < M_) ? b2f(k[((size_t)(b * M_ + m)) * C_ + h * D_ + c]) : 0.0f;
    }
    __syncthreads();
    int tm = tid & 15, tn = tid >> 4;
    float s = 0.f;
#pragma unroll 8
    for (int c = 0; c < 96; c++) s += Qs[tn][c] * Ks[tm][c];
    int n = nt * 16 + tn, m = mt * 16 + tm;
    if (n < N_ && m < M_) {
        const float scale = 0.10206207261596575f;  // 96^-0.5
        float z = s * scale;
        o[(((size_t)b * H_ + h) * N_ + n) * M_ + m] = 1.0f / (1.0f + expf(-z));
    }
}

// ---------------- cbuf[b,m,h*D+d] = sum_n o[b,h,n,m] * cg[b,n,h*D+d]  (bf16 out) ----------------
__global__ __launch_bounds__(256) void pool_kernel(
    const float* __restrict__ o, const bf16* __restrict__ cg,
    bf16* __restrict__ cbuf)
{
    int dt = blockIdx.x % 6;
    int mt = (blockIdx.x / 6) % 13;
    int h  = (blockIdx.x / 78) % H_;
    int b  = blockIdx.x / (78 * H_);
    __shared__ float Os[16][17];
    __shared__ float Cs[16][17];
    int tid = threadIdx.x;
    int tm = tid & 15, td = tid >> 4;
    float acc = 0.f;
    for (int n0 = 0; n0 < N_; n0 += 16) {
        int n = n0 + (tid >> 4);
        int m = mt * 16 + (tid & 15);
        Os[tid >> 4][tid & 15] = (n < N_ && m < M_)
            ? o[(((size_t)b * H_ + h) * N_ + n) * M_ + m] : 0.0f;
        int dd = dt * 16 + (tid & 15);
        Cs[tid >> 4][tid & 15] = (n < N_)
            ? b2f(cg[((size_t)b * N_ + n) * C_ + h * D_ + dd]) : 0.0f;
        __syncthreads();
#pragma unroll
        for (int nn = 0; nn < 16; nn++) acc += Os[nn][tm] * Cs[nn][td];
        __syncthreads();
    }
    int m = mt * 16 + tm, dd = dt * 16 + td;
    if (m < M_) cbuf[((size_t)b * M_ + m) * C_ + h * D_ + dd] = __float2bfloat16(acc);
}

// ---------------- gate[b,h,m] = 1 - mean_n o[b,h,n,m] ----------------
__global__ __launch_bounds__(256) void gate_kernel(const float* __restrict__ o,
                                                   float* __restrict__ gate)
{
    int h = blockIdx.x % H_, b = blockIdx.x / H_;
    int m = threadIdx.x;
    if (m < M_) {
        const float* p = o + ((size_t)(b * H_ + h)) * N_ * M_ + m;
        float s = 0.f;
        for (int n = 0; n < N_; n++) s += p[(size_t)n * M_];
        gate[(b * H_ + h) * M_ + m] = 1.0f - s * (1.0f / N_);
    }
}

// ---------------- new_mem = LN(part0+part1+bias + gate*memh) -> mem_bf (+ d_out) ----------------
__global__ __launch_bounds__(256) void final_kernel(
    const float* __restrict__ part, const float* __restrict__ p_b2,
    const float* __restrict__ gate, const bf16* __restrict__ memh,
    const float* __restrict__ w, const float* __restrict__ bia,
    bf16* __restrict__ mem_bf, float* __restrict__ outp)
{
    __shared__ float sdata[256];
    int row = blockIdx.x;          // b*M + m
    int b = row / M_, m = row % M_;
    float x[3];
    float sum = 0.f, sumsq = 0.f;
#pragma unroll
    for (int i = 0; i < 3; i++) {
        int c = threadIdx.x + i * 256;
        int h = c / D_;
        float v = part[(size_t)row * C_ + c] + part[(size_t)MP_ * C_ + (size_t)row * C_ + c]
                + p_b2[c]
                + gate[(b * H_ + h) * M_ + m] * b2f(memh[(size_t)row * C_ + c]);
        x[i] = v;
        sum += v; sumsq += v * v;
    }
    sum = block_reduce_sum256(sum, sdata);
    sumsq = block_reduce_sum256(sumsq, sdata);
    float mu = sum * (1.0f / C_);
    float var = sumsq * (1.0f / C_) - mu * mu;
    float rs = rsqrtf(var + 1e-5f);
#pragma unroll
    for (int i = 0; i < 3; i++) {
        int c = threadIdx.x + i * 256;
        float v = (x[i] - mu) * rs * w[c] + bia[c];
        mem_bf[(size_t)row * C_ + c] = __float2bfloat16(v);
        if (outp) outp[(size_t)row * C_ + c] = v;
    }
}

extern "C" void kernel_launch(void* const* d_in, const int* in_sizes, int n_in,
                              void* d_out, int out_size, void* d_ws, size_t ws_size,
                              hipStream_t stream)
{
    const float* cur_fea = (const float*)d_in[0];
    const float* n1w = (const float*)d_in[1];
    const float* n1b = (const float*)d_in[2];
    const float* n2w = (const float*)d_in[3];
    const float* n2b = (const float*)d_in[4];
    const float* c_w1 = (const float*)d_in[5];
    const float* c_b1 = (const float*)d_in[6];
    const float* c_w2 = (const float*)d_in[7];
    const float* c_b2 = (const float*)d_in[8];
    const float* m_w1 = (const float*)d_in[9];
    const float* m_b1 = (const float*)d_in[10];
    const float* m_w2 = (const float*)d_in[11];
    const float* m_b2 = (const float*)d_in[12];
    const float* p_w1 = (const float*)d_in[13];
    const float* p_b1 = (const float*)d_in[14];
    const float* p_w2 = (const float*)d_in[15];
    const float* p_b2 = (const float*)d_in[16];
    const float* q_w = (const float*)d_in[17];
    const float* q_b = (const float*)d_in[18];
    const float* k_w = (const float*)d_in[19];
    const float* k_b = (const float*)d_in[20];

    // ---- workspace carve (256B-aligned), total ~68 MiB ----
    size_t off = 0;
    char* base = (char*)d_ws;
    auto carve = [&](size_t bytes) -> char* {
        char* r = base + off;
        off += (bytes + 255) & ~(size_t)255;
        return r;
    };
    bf16* cw1t = (bf16*)carve((size_t)HID_ * (2 * C_) * 2);   // [3072,1536]
    bf16* cw2t = (bf16*)carve((size_t)C_ * HID_ * 2);         // [768,3072]
    bf16* mw1t = (bf16*)carve((size_t)HID_ * C_ * 2);
    bf16* mw2t = (bf16*)carve((size_t)C_ * HID_ * 2);
    bf16* pw1t = (bf16*)carve((size_t)HID_ * C_ * 2);
    bf16* pw2t = (bf16*)carve((size_t)C_ * HID_ * 2);
    bf16* qwt  = (bf16*)carve((size_t)C_ * C_ * 2);
    bf16* kwt  = (bf16*)carve((size_t)C_ * C_ * 2);
    bf16* mem_bf = (bf16*)carve((size_t)MP_ * C_ * 2);
    char* catreg = carve((size_t)MP_ * 2 * C_ * 2);           // cat; later qb|kb
    bf16* cat = (bf16*)catreg;
    bf16* qb  = (bf16*)catreg;                                // alias (cat dead after G1)
    bf16* kb  = (bf16*)catreg + (size_t)MP_ * C_;             // alias (written in G2, after G1)
    bf16* hid_c = (bf16*)carve((size_t)MP_ * HID_ * 2);       // c1 out; p1 out
    char* hidm_reg = carve((size_t)MP_ * HID_ * 2);           // m1 out; ob; p2 partials
    bf16*  hid_m = (bf16*)hidm_reg;
    float* ob    = (float*)hidm_reg;                          // 9.38MiB <= 9.75MiB
    float* part  = (float*)hidm_reg;                          // 2*MP_*C_*4 = 9.75MiB exactly
    bf16* cg    = (bf16*)carve((size_t)MP_ * C_ * 2);
    bf16* cbuf  = (bf16*)carve((size_t)MP_ * C_ * 2);
    bf16* memh  = (bf16*)carve((size_t)MP_ * C_ * 2);
    float* ap   = (float*)carve((size_t)B_ * C_ * 4);
    float* gateb = (float*)carve((size_t)B_ * H_ * M_ * 4);

    const dim3 blk(256);

    // ---- weight convert + transpose (once per call) ----
    transpose_cvt_kernel<<<dim3(HID_ / 32, (2 * C_) / 32), blk, 0, stream>>>(c_w1, cw1t, 2 * C_, HID_);
    transpose_cvt_kernel<<<dim3(C_ / 32, HID_ / 32), blk, 0, stream>>>(c_w2, cw2t, HID_, C_);
    transpose_cvt_kernel<<<dim3(HID_ / 32, C_ / 32), blk, 0, stream>>>(m_w1, mw1t, C_, HID_);
    transpose_cvt_kernel<<<dim3(C_ / 32, HID_ / 32), blk, 0, stream>>>(m_w2, mw2t, HID_, C_);
    transpose_cvt_kernel<<<dim3(HID_ / 32, C_ / 32), blk, 0, stream>>>(p_w1, pw1t, C_, HID_);
    transpose_cvt_kernel<<<dim3(C_ / 32, HID_ / 32), blk, 0, stream>>>(p_w2, pw2t, HID_, C_);
    transpose_cvt_kernel<<<dim3(C_ / 32, C_ / 32), blk, 0, stream>>>(q_w, qwt, C_, C_);
    transpose_cvt_kernel<<<dim3(C_ / 32, C_ / 32), blk, 0, stream>>>(k_w, kwt, C_, C_);

    // ---- init memory = LN(frame 0) ----
    ln_frame_kernel<<<ROWS_, blk, 0, stream>>>(cur_fea, 0, n1w, n1b, mem_bf);

    for (int t = 1; t < T_; t++) {
        ap_kernel<<<B_, 768, 0, stream>>>(mem_bf, ap);
        build_cat_kernel<<<ROWS_, blk, 0, stream>>>(cur_fea, t, n1w, n1b, ap, cat);

        // G1: c1 + m1 batched (624 blocks). NOTE: k-proj must NOT be here —
        // kb aliases the upper half of cat, which c1 is still reading.
        {
            GemmDescs ds;
            ds.d[0] = { cat,    cw1t, c_b1, hid_c, 2 * C_, HID_, HID_ / 128, 1 };
            ds.d[1] = { mem_bf, mw1t, m_b1, hid_m, C_,     HID_, HID_ / 128, 1 };
            ds.d[2] = ds.d[0];
            mfma_gemm_multi<128><<<dim3(MP_ / 128, HID_ / 128, 2), blk, 0, stream>>>(ds);
        }
        // G2: c2 + m2 + k batched (468 blocks). cat fully consumed by G1,
        // so kb's alias of catreg's upper half is now dead storage.
        {
            GemmDescs ds;
            ds.d[0] = { hid_c,  cw2t, c_b2, cg,   HID_, C_, C_ / 64, 0 };
            ds.d[1] = { hid_m,  mw2t, m_b2, memh, HID_, C_, C_ / 64, 0 };
            ds.d[2] = { mem_bf, kwt,  k_b,  kb,   C_,   C_, C_ / 64, 0 };
            mfma_gemm_multi<64><<<dim3(MP_ / 128, C_ / 64, 3), blk, 0, stream>>>(ds);
        }
        // q projection (depends on cg; qb aliases lower half of dead cat)
        {
            GemmDescs ds;
            ds.d[0] = { cg, qwt, q_b, qb, C_, C_, C_ / 64, 0 };
            ds.d[1] = ds.d[0]; ds.d[2] = ds.d[0];
            mfma_gemm_multi<64><<<dim3(MP_ / 128, C_ / 64, 1), blk, 0, stream>>>(ds);
        }
        // sigmoid attention + pooling + gate (ob overwrites hid_m — consumed by G2)
        attn_kernel<<<B_ * H_ * 13 * 13, blk, 0, stream>>>(qb, kb, ob);
        pool_kernel<<<B_ * H_ * 13 * 6, blk, 0, stream>>>(ob, cg, cbuf);
        gate_kernel<<<B_ * H_, blk, 0, stream>>>(ob, gateb);
        // p1 (312 blocks) into hid_c
        {
            GemmDescs ds;
            ds.d[0] = { cbuf, pw1t, p_b1, hid_c, C_, HID_, HID_ / 128, 1 };
            ds.d[1] = ds.d[0]; ds.d[2] = ds.d[0];
            mfma_gemm_multi<128><<<dim3(MP_ / 128, HID_ / 128, 1), blk, 0, stream>>>(ds);
        }
        // p2 split-K=2 -> fp32 partials (over ob region — consumed above)
        mfma_gemm_splitk<<<dim3(MP_ / 128, C_ / 64, 2), blk, 0, stream>>>(hid_c, pw2t, part, HID_);
        // residual gate + LN -> new mem (sums partials + bias inline)
        final_kernel<<<ROWS_, blk, 0, stream>>>(part, p_b2, gateb, memh, n2w, n2b,
                                                mem_bf, (t == T_ - 1) ? (float*)d_out : nullptr);
    }
}

// Round 6
// 4349.594 us; speedup vs baseline: 6.2323x; 1.0813x over previous
//
#include <hip/hip_runtime.h>
#include <hip/hip_bf16.h>
#include <math.h>

// Problem dims
constexpr int B_   = 8;
constexpr int T_   = 16;
constexpr int N_   = 196;
constexpr int C_   = 768;
constexpr int H_   = 8;
constexpr int D_   = 96;
constexpr int M_   = 196;    // MEM
constexpr int HID_ = 3072;
constexpr int ROWS_ = B_ * N_;   // 1568 == B_*M_
constexpr int MP_   = 1664;      // ROWS_ padded to multiple of 128 (13*128)

typedef __hip_bfloat16 bf16;
typedef __attribute__((ext_vector_type(8))) short bf16x8;
typedef __attribute__((ext_vector_type(4))) float f32x4;

__device__ __forceinline__ float b2f(bf16 x) { return __bfloat162float(x); }

#define GL2LDS(g, l) __builtin_amdgcn_global_load_lds( \
    (__attribute__((address_space(1))) void*)(g), \
    (__attribute__((address_space(3))) void*)(l), 16, 0, 0)

// Raw block barrier WITHOUT the __syncthreads vmcnt(0) drain. Compiler-level
// memory clobbers on both sides pin GL2LDS / ds_read motion.
__device__ __forceinline__ void hard_barrier() {
    asm volatile("" ::: "memory");
    __builtin_amdgcn_s_barrier();
    asm volatile("" ::: "memory");
}

// ---------------- block reduction (256 threads) ----------------
__device__ __forceinline__ float block_reduce_sum256(float v, float* sdata) {
    int tid = threadIdx.x;
    sdata[tid] = v;
    __syncthreads();
    for (int s = 128; s > 0; s >>= 1) {
        if (tid < s) sdata[tid] += sdata[tid + s];
        __syncthreads();
    }
    float r = sdata[0];
    __syncthreads();
    return r;
}

// ---------------- weight convert + transpose: W[K,N] fp32 -> Wt[N,K] bf16 ----------------
__global__ __launch_bounds__(256) void transpose_cvt_kernel(
    const float* __restrict__ W, bf16* __restrict__ Wt, int K, int N)
{
    __shared__ float tile[32][33];
    int tx = threadIdx.x & 31, ty = threadIdx.x >> 5;
    int n0 = blockIdx.x * 32, k0 = blockIdx.y * 32;
#pragma unroll
    for (int i = 0; i < 32; i += 8)
        tile[ty + i][tx] = W[(size_t)(k0 + ty + i) * N + n0 + tx];
    __syncthreads();
#pragma unroll
    for (int i = 0; i < 32; i += 8)
        Wt[(size_t)(n0 + ty + i) * K + k0 + tx] = __float2bfloat16(tile[tx][ty + i]);
}

// ---------------- elementwise fp32 -> bf16 ----------------
__global__ __launch_bounds__(256) void cvt_kernel(const float* __restrict__ W,
                                                  bf16* __restrict__ o, int n)
{
    int i = blockIdx.x * 256 + threadIdx.x;
    if (i < n) o[i] = __float2bfloat16(W[i]);
}

// ---------------- LN of frame 0 -> mem_bf (bf16) ----------------
__global__ __launch_bounds__(256) void ln_frame_kernel(
    const float* __restrict__ cur, int t,
    const float* __restrict__ w, const float* __restrict__ bia,
    bf16* __restrict__ mem_bf)
{
    __shared__ float sdata[256];
    int row = blockIdx.x;
    int b = row / N_, n = row % N_;
    const float* src = cur + (((size_t)b * T_ + t) * N_ + n) * C_;
    float x[3];
    float sum = 0.f, sumsq = 0.f;
#pragma unroll
    for (int i = 0; i < 3; i++) {
        int c = threadIdx.x + i * 256;
        x[i] = src[c];
        sum += x[i]; sumsq += x[i] * x[i];
    }
    sum = block_reduce_sum256(sum, sdata);
    sumsq = block_reduce_sum256(sumsq, sdata);
    float mu = sum * (1.0f / C_);
    float var = sumsq * (1.0f / C_) - mu * mu;
    float rs = rsqrtf(var + 1e-5f);
#pragma unroll
    for (int i = 0; i < 3; i++) {
        int c = threadIdx.x + i * 256;
        mem_bf[(size_t)row * C_ + c] = __float2bfloat16((x[i] - mu) * rs * w[c] + bia[c]);
    }
}

// ---------------- ap[b,c] = mean_m mem[b,m,c] (bf16 in, fp32 out) ----------------
__global__ __launch_bounds__(768) void ap_kernel(const bf16* __restrict__ mem,
                                                 float* __restrict__ ap)
{
    int b = blockIdx.x;
    int c = threadIdx.x;
    const bf16* p = mem + (size_t)b * M_ * C_ + c;
    float s = 0.f;
    for (int m = 0; m < M_; m++) s += b2f(p[(size_t)m * C_]);
    ap[b * C_ + c] = s * (1.0f / M_);
}

// ---------------- cat[row,0:C]=LN(frame t), cat[row,C:2C]=ap[b]  (bf16) ----------------
__global__ __launch_bounds__(256) void build_cat_kernel(
    const float* __restrict__ cur, int t,
    const float* __restrict__ w, const float* __restrict__ bia,
    const float* __restrict__ ap, bf16* __restrict__ cat)
{
    __shared__ float sdata[256];
    int row = blockIdx.x;
    int b = row / N_, n = row % N_;
    const float* src = cur + (((size_t)b * T_ + t) * N_ + n) * C_;
    float x[3];
    float sum = 0.f, sumsq = 0.f;
#pragma unroll
    for (int i = 0; i < 3; i++) {
        int c = threadIdx.x + i * 256;
        x[i] = src[c];
        sum += x[i]; sumsq += x[i] * x[i];
    }
    sum = block_reduce_sum256(sum, sdata);
    sumsq = block_reduce_sum256(sumsq, sdata);
    float mu = sum * (1.0f / C_);
    float var = sumsq * (1.0f / C_) - mu * mu;
    float rs = rsqrtf(var + 1e-5f);
    bf16* dstrow = cat + (size_t)row * (2 * C_);
#pragma unroll
    for (int i = 0; i < 3; i++) {
        int c = threadIdx.x + i * 256;
        dstrow[c] = __float2bfloat16((x[i] - mu) * rs * w[c] + bia[c]);
        dstrow[C_ + c] = __float2bfloat16(ap[b * C_ + c]);
    }
}

// ---------------- batched MFMA GEMM, 2-deep pipelined (up to 4 subproblems) ----------------
// out[*,N](bf16) = A[*,K](bf16) x Wt[N,K]^T (+ bias) ; optional GELU.
// BM=128, BK=32. 256 threads = 4 waves (2x2). Double-buffered LDS with raw
// s_barrier + vmcnt(NL): prefetch for tile k+1 stays in flight across the
// barrier (no vmcnt(0) drain) — critical at ~1 block/CU occupancy.
struct GemmDesc {
    const bf16* A; const bf16* W; const float* bias; bf16* out;
    int K; int N; int ymax; int gelu;
};
struct GemmDescs { GemmDesc d[4]; };

template <int BN>
__global__ __launch_bounds__(256) void mfma_gemm_multi(GemmDescs ds)
{
    constexpr int BM = 128;
    constexpr int BK = 32;
    constexpr int TI = 4;
    constexpr int TJ = (BN / 2) / 16;
    constexpr int AR = (BM * 64) / 4096;    // staging rounds for A (2)
    constexpr int BR = (BN * 64) / 4096;    // staging rounds for B (2 or 1)
    constexpr int NL = AR + BR;             // loads per wave per tile
    __shared__ short As[2 * BM * BK];
    __shared__ short Bs[2 * BN * BK];

    GemmDesc g = ds.d[blockIdx.z];
    if ((int)blockIdx.y >= g.ymax) return;

    int tid = threadIdx.x;
    int wid = tid >> 6;
    int lane = tid & 63;
    int quad = lane >> 4, l15 = lane & 15;
    int row0 = blockIdx.x * BM;
    int col0 = blockIdx.y * BN;
    int wm = (wid >> 1) * 64;
    int wn = (wid & 1) * (BN / 2);

    f32x4 acc[TI][TJ] = {};

    const char* Ab = (const char*)g.A;
    const char* Wb = (const char*)g.W;
    const size_t Kb = (size_t)g.K * 2;
    const int base = wid * 1024;

    auto stage = [&](int k0, int sel) {
        char* Ad = (char*)As + sel * (BM * 64);
        char* Bd = (char*)Bs + sel * (BN * 64);
#pragma unroll
        for (int r = 0; r < AR; r++) {
            int byteidx = base + r * 4096 + lane * 16;
            int row = byteidx >> 6, kbyte = byteidx & 63;
            GL2LDS(Ab + (size_t)(row0 + row) * Kb + (size_t)k0 * 2 + kbyte,
                   Ad + base + r * 4096);
        }
#pragma unroll
        for (int r = 0; r < BR; r++) {
            int byteidx = base + r * 4096 + lane * 16;
            int n = byteidx >> 6, kbyte = byteidx & 63;
            GL2LDS(Wb + (size_t)(col0 + n) * Kb + (size_t)k0 * 2 + kbyte,
                   Bd + base + r * 4096);
        }
    };

    const int nk = g.K / BK;
    stage(0, 0);
    for (int ki = 0; ki < nk; ki++) {
        int sel = ki & 1;
        if (ki + 1 < nk) {
            stage((ki + 1) * BK, sel ^ 1);
            asm volatile("s_waitcnt vmcnt(%0)" :: "n"(NL) : "memory");  // tile ki done; prefetch in flight
        } else {
            asm volatile("s_waitcnt vmcnt(0)" ::: "memory");
        }
        hard_barrier();
        const bf16x8* Av = (const bf16x8*)(As + sel * BM * BK);
        const bf16x8* Bv = (const bf16x8*)(Bs + sel * BN * BK);
        bf16x8 af[TI], bfr[TJ];
#pragma unroll
        for (int i = 0; i < TI; i++)
            af[i] = Av[(wm + i * 16 + l15) * (BK / 8) + quad];
#pragma unroll
        for (int j = 0; j < TJ; j++)
            bfr[j] = Bv[(wn + j * 16 + l15) * (BK / 8) + quad];
#pragma unroll
        for (int i = 0; i < TI; i++)
#pragma unroll
            for (int j = 0; j < TJ; j++)
                acc[i][j] = __builtin_amdgcn_mfma_f32_16x16x32_bf16(
                    af[i], bfr[j], acc[i][j], 0, 0, 0);
        hard_barrier();   // all reads of buf[sel] retired before iter ki+1 restages it
    }

    // epilogue: C/D layout col=lane&15, row=quad*4+reg
#pragma unroll
    for (int i = 0; i < TI; i++) {
        int gr = row0 + wm + i * 16 + quad * 4;
#pragma unroll
        for (int j = 0; j < TJ; j++) {
            int gc = col0 + wn + j * 16 + l15;
            float bv = g.bias ? g.bias[gc] : 0.0f;
#pragma unroll
            for (int r = 0; r < 4; r++) {
                float v = acc[i][j][r] + bv;
                if (g.gelu) v = 0.5f * v * (1.0f + erff(v * 0.7071067811865475f));
                g.out[(size_t)(gr + r) * g.N + gc] = __float2bfloat16(v);
            }
        }
    }
}

// ---------------- split-K MFMA GEMM for p2 (pipelined): part[z][MP_,768] fp32 ----------------
__global__ __launch_bounds__(256) void mfma_gemm_splitk(
    const bf16* __restrict__ A, const bf16* __restrict__ Wt,
    float* __restrict__ part, int K)
{
    constexpr int BM = 128;
    constexpr int BN = 64;
    constexpr int BK = 32;
    constexpr int TI = 4;
    constexpr int TJ = 2;
    constexpr int AR = 2, BR = 1, NL = 3;
    __shared__ short As[2 * BM * BK];
    __shared__ short Bs[2 * BN * BK];

    int tid = threadIdx.x;
    int wid = tid >> 6;
    int lane = tid & 63;
    int quad = lane >> 4, l15 = lane & 15;
    int row0 = blockIdx.x * BM;
    int col0 = blockIdx.y * BN;
    int wm = (wid >> 1) * 64;
    int wn = (wid & 1) * (BN / 2);
    int kh = K >> 1;
    int kbeg = blockIdx.z * kh;

    f32x4 acc[TI][TJ] = {};
    const char* Ab = (const char*)A;
    const char* Wb = (const char*)Wt;
    const size_t Kb = (size_t)K * 2;
    const int base = wid * 1024;

    auto stage = [&](int k0, int sel) {
        char* Ad = (char*)As + sel * (BM * 64);
        char* Bd = (char*)Bs + sel * (BN * 64);
#pragma unroll
        for (int r = 0; r < AR; r++) {
            int byteidx = base + r * 4096 + lane * 16;
            int row = byteidx >> 6, kbyte = byteidx & 63;
            GL2LDS(Ab + (size_t)(row0 + row) * Kb + (size_t)k0 * 2 + kbyte,
                   Ad + base + r * 4096);
        }
#pragma unroll
        for (int r = 0; r < BR; r++) {
            int byteidx = base + r * 4096 + lane * 16;
            int n = byteidx >> 6, kbyte = byteidx & 63;
            GL2LDS(Wb + (size_t)(col0 + n) * Kb + (size_t)k0 * 2 + kbyte,
                   Bd + base + r * 4096);
        }
    };

    const int nk = kh / BK;
    stage(kbeg, 0);
    for (int ki = 0; ki < nk; ki++) {
        int sel = ki & 1;
        if (ki + 1 < nk) {
            stage(kbeg + (ki + 1) * BK, sel ^ 1);
            asm volatile("s_waitcnt vmcnt(%0)" :: "n"(NL) : "memory");
        } else {
            asm volatile("s_waitcnt vmcnt(0)" ::: "memory");
        }
        hard_barrier();
        const bf16x8* Av = (const bf16x8*)(As + sel * BM * BK);
        const bf16x8* Bv = (const bf16x8*)(Bs + sel * BN * BK);
        bf16x8 af[TI], bfr[TJ];
#pragma unroll
        for (int i = 0; i < TI; i++)
            af[i] = Av[(wm + i * 16 + l15) * (BK / 8) + quad];
#pragma unroll
        for (int j = 0; j < TJ; j++)
            bfr[j] = Bv[(wn + j * 16 + l15) * (BK / 8) + quad];
#pragma unroll
        for (int i = 0; i < TI; i++)
#pragma unroll
            for (int j = 0; j < TJ; j++)
                acc[i][j] = __builtin_amdgcn_mfma_f32_16x16x32_bf16(
                    af[i], bfr[j], acc[i][j], 0, 0, 0);
        hard_barrier();
    }

    float* outp = part + (size_t)blockIdx.z * MP_ * C_;
#pragma unroll
    for (int i = 0; i < TI; i++) {
        int gr = row0 + wm + i * 16 + quad * 4;
#pragma unroll
        for (int j = 0; j < TJ; j++) {
            int gc = col0 + wn + j * 16 + l15;
#pragma unroll
            for (int r = 0; r < 4; r++)
                outp[(size_t)(gr + r) * C_ + gc] = acc[i][j][r];
        }
    }
}

// ---------------- b2q[n] = q_b[n] + sum_j c_b2[j] * W2q_t[n,j] ----------------
__global__ __launch_bounds__(64) void b2q_kernel(
    const float* __restrict__ c_b2, const float* __restrict__ q_b,
    const bf16* __restrict__ W2q_t, float* __restrict__ b2q)
{
    int n = blockIdx.x * 64 + threadIdx.x;
    float s = q_b[n];
    const bf16* row = W2q_t + (size_t)n * HID_;
    for (int j = 0; j < HID_; j++) s += c_b2[j] * b2f(row[j]);
    b2q[n] = s;
}

// ---------------- attention: o[b,h,n,m] = sigmoid(scale * q.k)  (q,k bf16) ----------------
__global__ __launch_bounds__(256) void attn_kernel(
    const bf16* __restrict__ q, const bf16* __restrict__ k,
    float* __restrict__ o)
{
    int mt = blockIdx.x % 13;
    int nt = (blockIdx.x / 13) % 13;
    int h  = (blockIdx.x / 169) % H_;
    int b  = blockIdx.x / (169 * H_);
    __shared__ float Qs[16][100];
    __shared__ float Ks[16][100];
    int tid = threadIdx.x;
    for (int idx = tid; idx < 16 * 96; idx += 256) {
        int r = idx / 96, c = idx % 96;
        int n = nt * 16 + r;
        Qs[r][c] = (n < N_) ? b2f(q[((size_t)(b * N_ + n)) * C_ + h * D_ + c]) : 0.0f;
        int m = mt * 16 + r;
        Ks[r][c] = (m < M_) ? b2f(k[((size_t)(b * M_ + m)) * C_ + h * D_ + c]) : 0.0f;
    }
    __syncthreads();
    int tm = tid & 15, tn = tid >> 4;
    float s = 0.f;
#pragma unroll 8
    for (int c = 0; c < 96; c++) s += Qs[tn][c] * Ks[tm][c];
    int n = nt * 16 + tn, m = mt * 16 + tm;
    if (n < N_ && m < M_) {
        const float scale = 0.10206207261596575f;  // 96^-0.5
        float z = s * scale;
        o[(((size_t)b * H_ + h) * N_ + n) * M_ + m] = 1.0f / (1.0f + expf(-z));
    }
}

// ---------------- pool (+fused gate on dt==0 blocks) ----------------
// cbuf[b,m,h*D+d] = sum_n o[b,h,n,m] * cg[b,n,h*D+d]; gate[b,h,m]=1-mean_n o
__global__ __launch_bounds__(256) void pool_kernel(
    const float* __restrict__ o, const bf16* __restrict__ cg,
    bf16* __restrict__ cbuf, float* __restrict__ gate)
{
    int dt = blockIdx.x % 6;
    int mt = (blockIdx.x / 6) % 13;
    int h  = (blockIdx.x / 78) % H_;
    int b  = blockIdx.x / (78 * H_);
    __shared__ float Os[16][17];
    __shared__ float Cs[16][17];
    int tid = threadIdx.x;
    int tm = tid & 15, td = tid >> 4;
    float acc = 0.f;
    float gsum = 0.f;
    for (int n0 = 0; n0 < N_; n0 += 16) {
        int n = n0 + (tid >> 4);
        int m = mt * 16 + (tid & 15);
        Os[tid >> 4][tid & 15] = (n < N_ && m < M_)
            ? o[(((size_t)b * H_ + h) * N_ + n) * M_ + m] : 0.0f;
        int dd = dt * 16 + (tid & 15);
        Cs[tid >> 4][tid & 15] = (n < N_)
            ? b2f(cg[((size_t)b * N_ + n) * C_ + h * D_ + dd]) : 0.0f;
        __syncthreads();
#pragma unroll
        for (int nn = 0; nn < 16; nn++) acc += Os[nn][tm] * Cs[nn][td];
        if (dt == 0 && td == 0) {
#pragma unroll
            for (int nn = 0; nn < 16; nn++) gsum += Os[nn][tm];
        }
        __syncthreads();
    }
    int m = mt * 16 + tm, dd = dt * 16 + td;
    if (m < M_) {
        cbuf[((size_t)b * M_ + m) * C_ + h * D_ + dd] = __float2bfloat16(acc);
        if (dt == 0 && td == 0)
            gate[(b * H_ + h) * M_ + m] = 1.0f - gsum * (1.0f / N_);
    }
}

// ---------------- new_mem = LN(part0+part1+bias + gate*memh) -> mem_bf (+ d_out) ----------------
__global__ __launch_bounds__(256) void final_kernel(
    const float* __restrict__ part, const float* __restrict__ p_b2,
    const float* __restrict__ gate, const bf16* __restrict__ memh,
    const float* __restrict__ w, const float* __restrict__ bia,
    bf16* __restrict__ mem_bf, float* __restrict__ outp)
{
    __shared__ float sdata[256];
    int row = blockIdx.x;
    int b = row / M_, m = row % M_;
    float x[3];
    float sum = 0.f, sumsq = 0.f;
#pragma unroll
    for (int i = 0; i < 3; i++) {
        int c = threadIdx.x + i * 256;
        int h = c / D_;
        float v = part[(size_t)row * C_ + c] + part[(size_t)MP_ * C_ + (size_t)row * C_ + c]
                + p_b2[c]
                + gate[(b * H_ + h) * M_ + m] * b2f(memh[(size_t)row * C_ + c]);
        x[i] = v;
        sum += v; sumsq += v * v;
    }
    sum = block_reduce_sum256(sum, sdata);
    sumsq = block_reduce_sum256(sumsq, sdata);
    float mu = sum * (1.0f / C_);
    float var = sumsq * (1.0f / C_) - mu * mu;
    float rs = rsqrtf(var + 1e-5f);
#pragma unroll
    for (int i = 0; i < 3; i++) {
        int c = threadIdx.x + i * 256;
        float v = (x[i] - mu) * rs * w[c] + bia[c];
        mem_bf[(size_t)row * C_ + c] = __float2bfloat16(v);
        if (outp) outp[(size_t)row * C_ + c] = v;
    }
}

extern "C" void kernel_launch(void* const* d_in, const int* in_sizes, int n_in,
                              void* d_out, int out_size, void* d_ws, size_t ws_size,
                              hipStream_t stream)
{
    const float* cur_fea = (const float*)d_in[0];
    const float* n1w = (const float*)d_in[1];
    const float* n1b = (const float*)d_in[2];
    const float* n2w = (const float*)d_in[3];
    const float* n2b = (const float*)d_in[4];
    const float* c_w1 = (const float*)d_in[5];
    const float* c_b1 = (const float*)d_in[6];
    const float* c_w2 = (const float*)d_in[7];
    const float* c_b2 = (const float*)d_in[8];
    const float* m_w1 = (const float*)d_in[9];
    const float* m_b1 = (const float*)d_in[10];
    const float* m_w2 = (const float*)d_in[11];
    const float* m_b2 = (const float*)d_in[12];
    const float* p_w1 = (const float*)d_in[13];
    const float* p_b1 = (const float*)d_in[14];
    const float* p_w2 = (const float*)d_in[15];
    const float* p_b2 = (const float*)d_in[16];
    const float* q_w = (const float*)d_in[17];
    const float* q_b = (const float*)d_in[18];
    const float* k_w = (const float*)d_in[19];
    const float* k_b = (const float*)d_in[20];

    // ---- workspace carve (256B-aligned) ----
    size_t off = 0;
    char* base = (char*)d_ws;
    auto carve = [&](size_t bytes) -> char* {
        char* r = base + off;
        off += (bytes + 255) & ~(size_t)255;
        return r;
    };
    bf16* cw1t = (bf16*)carve((size_t)HID_ * (2 * C_) * 2);
    bf16* cw2t = (bf16*)carve((size_t)C_ * HID_ * 2);
    bf16* mw1t = (bf16*)carve((size_t)HID_ * C_ * 2);
    bf16* mw2t = (bf16*)carve((size_t)C_ * HID_ * 2);
    bf16* pw1t = (bf16*)carve((size_t)HID_ * C_ * 2);
    bf16* pw2t = (bf16*)carve((size_t)C_ * HID_ * 2);
    bf16* qwt  = (bf16*)carve((size_t)C_ * C_ * 2);
    bf16* kwt  = (bf16*)carve((size_t)C_ * C_ * 2);
    bf16* mem_bf = (bf16*)carve((size_t)MP_ * C_ * 2);
    char* catreg = carve((size_t)MP_ * 2 * C_ * 2);           // cat; later qb|kb
    bf16* cat = (bf16*)catreg;
    bf16* qb  = (bf16*)catreg;                                // alias (cat dead after G1)
    bf16* kb  = (bf16*)catreg + (size_t)MP_ * C_;             // alias (written in G2)
    bf16* hid_c = (bf16*)carve((size_t)MP_ * HID_ * 2);       // c1/p1 out; cw2nt temp pre-loop
    char* hidm_reg = carve((size_t)MP_ * HID_ * 2);           // m1 out; ob; p2 partials
    bf16*  hid_m = (bf16*)hidm_reg;
    float* ob    = (float*)hidm_reg;
    float* part  = (float*)hidm_reg;
    bf16* cg    = (bf16*)carve((size_t)MP_ * C_ * 2);
    bf16* cbuf  = (bf16*)carve((size_t)MP_ * C_ * 2);
    bf16* memh  = (bf16*)carve((size_t)MP_ * C_ * 2);
    float* ap   = (float*)carve((size_t)B_ * C_ * 4);
    float* gateb = (float*)carve((size_t)B_ * H_ * M_ * 4);
    float* b2qb  = (float*)carve((size_t)C_ * 4);
    // fused-q extras carved last; enabled only if workspace is big enough
    bf16* W2q_t = (bf16*)carve((size_t)C_ * HID_ * 2);
    const bool fuse_q = (off <= ws_size);

    const dim3 blk(256);

    // ---- weight convert + transpose (once per call) ----
    transpose_cvt_kernel<<<dim3(HID_ / 32, (2 * C_) / 32), blk, 0, stream>>>(c_w1, cw1t, 2 * C_, HID_);
    transpose_cvt_kernel<<<dim3(C_ / 32, HID_ / 32), blk, 0, stream>>>(c_w2, cw2t, HID_, C_);
    transpose_cvt_kernel<<<dim3(HID_ / 32, C_ / 32), blk, 0, stream>>>(m_w1, mw1t, C_, HID_);
    transpose_cvt_kernel<<<dim3(C_ / 32, HID_ / 32), blk, 0, stream>>>(m_w2, mw2t, HID_, C_);
    transpose_cvt_kernel<<<dim3(HID_ / 32, C_ / 32), blk, 0, stream>>>(p_w1, pw1t, C_, HID_);
    transpose_cvt_kernel<<<dim3(C_ / 32, HID_ / 32), blk, 0, stream>>>(p_w2, pw2t, HID_, C_);
    transpose_cvt_kernel<<<dim3(C_ / 32, C_ / 32), blk, 0, stream>>>(q_w, qwt, C_, C_);
    transpose_cvt_kernel<<<dim3(C_ / 32, C_ / 32), blk, 0, stream>>>(k_w, kwt, C_, C_);

    if (fuse_q) {
        // W2q_t[n,j] = sum_l q_w[l,n] * c_w2[j,l]  == (c_w2 @ q_w)[j,n]
        // via out = A @ Wt^T with A=qwt[768,768], Wt=cvt(c_w2)[3072,768].
        bf16* cw2nt = hid_c;   // temp, pre-loop only
        cvt_kernel<<<(HID_ * C_ + 255) / 256, blk, 0, stream>>>(c_w2, cw2nt, HID_ * C_);
        GemmDescs ds;
        ds.d[0] = { qwt, cw2nt, nullptr, W2q_t, C_, HID_, HID_ / 128, 0 };
        ds.d[1] = ds.d[0]; ds.d[2] = ds.d[0]; ds.d[3] = ds.d[0];
        mfma_gemm_multi<128><<<dim3(C_ / 128, HID_ / 128, 1), blk, 0, stream>>>(ds);
        b2q_kernel<<<C_ / 64, 64, 0, stream>>>(c_b2, q_b, W2q_t, b2qb);
    }

    // ---- init memory = LN(frame 0) ----
    ln_frame_kernel<<<ROWS_, blk, 0, stream>>>(cur_fea, 0, n1w, n1b, mem_bf);

    for (int t = 1; t < T_; t++) {
        ap_kernel<<<B_, 768, 0, stream>>>(mem_bf, ap);
        build_cat_kernel<<<ROWS_, blk, 0, stream>>>(cur_fea, t, n1w, n1b, ap, cat);

        // G1: c1 + m1 (624 blocks). k-proj must NOT be here: kb aliases cat's
        // upper half which c1 is still reading (round-4 race).
        {
            GemmDescs ds;
            ds.d[0] = { cat,    cw1t, c_b1, hid_c, 2 * C_, HID_, HID_ / 128, 1 };
            ds.d[1] = { mem_bf, mw1t, m_b1, hid_m, C_,     HID_, HID_ / 128, 1 };
            ds.d[2] = ds.d[0]; ds.d[3] = ds.d[0];
            mfma_gemm_multi<128><<<dim3(MP_ / 128, HID_ / 128, 2), blk, 0, stream>>>(ds);
        }
        // G2: c2 + m2 + k (+ fused q from hid_c via W2q). cat dead after G1,
        // so qb/kb aliases are safe here.
        {
            GemmDescs ds;
            ds.d[0] = { hid_c,  cw2t, c_b2, cg,   HID_, C_, C_ / 64, 0 };
            ds.d[1] = { hid_m,  mw2t, m_b2, memh, HID_, C_, C_ / 64, 0 };
            ds.d[2] = { mem_bf, kwt,  k_b,  kb,   C_,   C_, C_ / 64, 0 };
            ds.d[3] = { hid_c,  W2q_t, b2qb, qb,  HID_, C_, C_ / 64, 0 };
            mfma_gemm_multi<64><<<dim3(MP_ / 128, C_ / 64, fuse_q ? 4 : 3), blk, 0, stream>>>(ds);
        }
        if (!fuse_q) {
            GemmDescs ds;
            ds.d[0] = { cg, qwt, q_b, qb, C_, C_, C_ / 64, 0 };
            ds.d[1] = ds.d[0]; ds.d[2] = ds.d[0]; ds.d[3] = ds.d[0];
            mfma_gemm_multi<64><<<dim3(MP_ / 128, C_ / 64, 1), blk, 0, stream>>>(ds);
        }
        // attention + pooling(+gate) — ob overwrites hid_m (consumed by G2)
        attn_kernel<<<B_ * H_ * 13 * 13, blk, 0, stream>>>(qb, kb, ob);
        pool_kernel<<<B_ * H_ * 13 * 6, blk, 0, stream>>>(ob, cg, cbuf, gateb);
        // p1 into hid_c
        {
            GemmDescs ds;
            ds.d[0] = { cbuf, pw1t, p_b1, hid_c, C_, HID_, HID_ / 128, 1 };
            ds.d[1] = ds.d[0]; ds.d[2] = ds.d[0]; ds.d[3] = ds.d[0];
            mfma_gemm_multi<128><<<dim3(MP_ / 128, HID_ / 128, 1), blk, 0, stream>>>(ds);
        }
        // p2 split-K=2 -> fp32 partials (over ob region — consumed above)
        mfma_gemm_splitk<<<dim3(MP_ / 128, C_ / 64, 2), blk, 0, stream>>>(hid_c, pw2t, part, HID_);
        // residual gate + LN -> new mem (sums partials + bias inline)
        final_kernel<<<ROWS_, blk, 0, stream>>>(part, p_b2, gateb, memh, n2w, n2b,
                                                mem_bf, (t == T_ - 1) ? (float*)d_out : nullptr);
    }
}

// Round 8
// 3696.761 us; speedup vs baseline: 7.3329x; 1.1766x over previous
//
#include <hip/hip_runtime.h>
#include <hip/hip_bf16.h>
#include <math.h>

// Problem dims
constexpr int B_   = 8;
constexpr int T_   = 16;
constexpr int N_   = 196;
constexpr int C_   = 768;
constexpr int H_   = 8;
constexpr int D_   = 96;
constexpr int M_   = 196;    // MEM
constexpr int HID_ = 3072;
constexpr int ROWS_ = B_ * N_;   // 1568 == B_*M_
constexpr int MP_   = 1664;      // ROWS_ padded to multiple of 128 (13*128)

typedef __hip_bfloat16 bf16;
typedef __attribute__((ext_vector_type(8))) short bf16x8;
typedef __attribute__((ext_vector_type(4))) float f32x4;

__device__ __forceinline__ float b2f(bf16 x) { return __bfloat162float(x); }

#define GL2LDS(g, l) __builtin_amdgcn_global_load_lds( \
    (__attribute__((address_space(1))) void*)(g), \
    (__attribute__((address_space(3))) void*)(l), 16, 0, 0)

// Raw block barrier WITHOUT the __syncthreads vmcnt(0) drain.
__device__ __forceinline__ void hard_barrier() {
    asm volatile("" ::: "memory");
    __builtin_amdgcn_s_barrier();
    asm volatile("" ::: "memory");
}

// ---------------- block reduction (256 threads) ----------------
__device__ __forceinline__ float block_reduce_sum256(float v, float* sdata) {
    int tid = threadIdx.x;
    sdata[tid] = v;
    __syncthreads();
    for (int s = 128; s > 0; s >>= 1) {
        if (tid < s) sdata[tid] += sdata[tid + s];
        __syncthreads();
    }
    float r = sdata[0];
    __syncthreads();
    return r;
}

// ---------------- batched weight transpose: W[K,N] fp32 -> Wt[N,K] bf16 ----------------
struct TEnt { const float* W; bf16* Wt; int K; int N; int tiles; };
struct TEnts { TEnt e[8]; };

__global__ __launch_bounds__(256) void transpose_all_kernel(TEnts tds)
{
    __shared__ float tile[32][33];
    // Correct sequential prefix walk (round-7 version could overrun to e[8]).
    int local = blockIdx.x;
    int i = 0;
    while (i < 7 && local >= tds.e[i].tiles) { local -= tds.e[i].tiles; ++i; }
    TEnt g = tds.e[i];
    int ntx = g.N / 32;
    int n0 = (local % ntx) * 32, k0 = (local / ntx) * 32;
    int tx = threadIdx.x & 31, ty = threadIdx.x >> 5;
#pragma unroll
    for (int r = 0; r < 32; r += 8)
        tile[ty + r][tx] = g.W[(size_t)(k0 + ty + r) * g.N + n0 + tx];
    __syncthreads();
#pragma unroll
    for (int r = 0; r < 32; r += 8)
        g.Wt[(size_t)(n0 + ty + r) * g.K + k0 + tx] = __float2bfloat16(tile[tx][ty + r]);
}

// ---------------- elementwise fp32 -> bf16 ----------------
__global__ __launch_bounds__(256) void cvt_kernel(const float* __restrict__ W,
                                                  bf16* __restrict__ o, int n)
{
    int i = blockIdx.x * 256 + threadIdx.x;
    if (i < n) o[i] = __float2bfloat16(W[i]);
}

// ---------------- LN of frame 0 -> mem_bf (bf16) ----------------
__global__ __launch_bounds__(256) void ln_frame_kernel(
    const float* __restrict__ cur, int t,
    const float* __restrict__ w, const float* __restrict__ bia,
    bf16* __restrict__ mem_bf)
{
    __shared__ float sdata[256];
    int row = blockIdx.x;
    int b = row / N_, n = row % N_;
    const float* src = cur + (((size_t)b * T_ + t) * N_ + n) * C_;
    float x[3];
    float sum = 0.f, sumsq = 0.f;
#pragma unroll
    for (int i = 0; i < 3; i++) {
        int c = threadIdx.x + i * 256;
        x[i] = src[c];
        sum += x[i]; sumsq += x[i] * x[i];
    }
    sum = block_reduce_sum256(sum, sdata);
    sumsq = block_reduce_sum256(sumsq, sdata);
    float mu = sum * (1.0f / C_);
    float var = sumsq * (1.0f / C_) - mu * mu;
    float rs = rsqrtf(var + 1e-5f);
#pragma unroll
    for (int i = 0; i < 3; i++) {
        int c = threadIdx.x + i * 256;
        mem_bf[(size_t)row * C_ + c] = __float2bfloat16((x[i] - mu) * rs * w[c] + bia[c]);
    }
}

// ---------------- ap[b,c] = mean_m mem[b,m,c] (bf16 in, fp32 out) ----------------
__global__ __launch_bounds__(768) void ap_kernel(const bf16* __restrict__ mem,
                                                 float* __restrict__ ap)
{
    int b = blockIdx.x;
    int c = threadIdx.x;
    const bf16* p = mem + (size_t)b * M_ * C_ + c;
    float s = 0.f;
    for (int m = 0; m < M_; m++) s += b2f(p[(size_t)m * C_]);
    ap[b * C_ + c] = s * (1.0f / M_);
}

// ---------------- cat[row,0:C]=LN(frame t), cat[row,C:2C]=ap[b]  (bf16) ----------------
__global__ __launch_bounds__(256) void build_cat_kernel(
    const float* __restrict__ cur, int t,
    const float* __restrict__ w, const float* __restrict__ bia,
    const float* __restrict__ ap, bf16* __restrict__ cat)
{
    __shared__ float sdata[256];
    int row = blockIdx.x;
    int b = row / N_, n = row % N_;
    const float* src = cur + (((size_t)b * T_ + t) * N_ + n) * C_;
    float x[3];
    float sum = 0.f, sumsq = 0.f;
#pragma unroll
    for (int i = 0; i < 3; i++) {
        int c = threadIdx.x + i * 256;
        x[i] = src[c];
        sum += x[i]; sumsq += x[i] * x[i];
    }
    sum = block_reduce_sum256(sum, sdata);
    sumsq = block_reduce_sum256(sumsq, sdata);
    float mu = sum * (1.0f / C_);
    float var = sumsq * (1.0f / C_) - mu * mu;
    float rs = rsqrtf(var + 1e-5f);
    bf16* dstrow = cat + (size_t)row * (2 * C_);
#pragma unroll
    for (int i = 0; i < 3; i++) {
        int c = threadIdx.x + i * 256;
        dstrow[c] = __float2bfloat16((x[i] - mu) * rs * w[c] + bia[c]);
        dstrow[C_ + c] = __float2bfloat16(ap[b * C_ + c]);
    }
}

// ---------------- batched MFMA GEMM, BK=64, XOR-swizzled LDS, pipelined ----------------
// out[*,N](bf16) = A[*,K](bf16) x Wt[N,K]^T (+ bias) ; optional GELU.
// LDS row = 128 B; chunk c of row r holds global k-chunk c^(r&7) — staged via
// source-permuted global_load_lds, read back with the same XOR.
struct GemmDesc {
    const bf16* A; const bf16* W; const float* bias; bf16* out;
    int K; int N; int ymax; int gelu;
};
struct GemmDescs { GemmDesc d[4]; };

template <int BN>
__global__ __launch_bounds__(256) void mfma_gemm_multi(GemmDescs ds)
{
    constexpr int BM = 128;
    constexpr int TI = 4;
    constexpr int TJ = (BN / 2) / 16;
    constexpr int ABYTES = BM * 128;          // 16384
    constexpr int BBYTES = BN * 128;          // 16384 / 8192
    constexpr int AR = ABYTES / 4096;         // 4
    constexpr int BR = BBYTES / 4096;         // 4 / 2
    constexpr int NL = AR + BR;
    __shared__ short As[2 * BM * 64];
    __shared__ short Bs[2 * BN * 64];

    GemmDesc g = ds.d[blockIdx.z];
    if ((int)blockIdx.y >= g.ymax) return;

    int tid = threadIdx.x;
    int wid = tid >> 6;
    int lane = tid & 63;
    int quad = lane >> 4, l15 = lane & 15;
    int row0 = blockIdx.x * BM;
    int col0 = blockIdx.y * BN;
    int wm = (wid >> 1) * 64;
    int wn = (wid & 1) * (BN / 2);

    f32x4 acc[TI][TJ] = {};

    const char* Ab = (const char*)g.A;
    const char* Wb = (const char*)g.W;
    const size_t Kb = (size_t)g.K * 2;
    const int base = wid * 1024;

    auto stage = [&](int k0, int sel) {
        char* Ad = (char*)As + sel * ABYTES;
        char* Bd = (char*)Bs + sel * BBYTES;
#pragma unroll
        for (int r = 0; r < AR; r++) {
            int o = r * 4096 + base + lane * 16;
            int row = o >> 7, cs = (o >> 4) & 7;
            int kc = cs ^ (row & 7);
            GL2LDS(Ab + (size_t)(row0 + row) * Kb + (size_t)k0 * 2 + kc * 16, Ad + o);
        }
#pragma unroll
        for (int r = 0; r < BR; r++) {
            int o = r * 4096 + base + lane * 16;
            int row = o >> 7, cs = (o >> 4) & 7;
            int kc = cs ^ (row & 7);
            GL2LDS(Wb + (size_t)(col0 + row) * Kb + (size_t)k0 * 2 + kc * 16, Bd + o);
        }
    };

    const int nk = g.K / 64;
    stage(0, 0);
    for (int ki = 0; ki < nk; ki++) {
        int sel = ki & 1;
        if (ki + 1 < nk) {
            stage((ki + 1) * 64, sel ^ 1);
            asm volatile("s_waitcnt vmcnt(%0)" :: "n"(NL) : "memory");
        } else {
            asm volatile("s_waitcnt vmcnt(0)" ::: "memory");
        }
        hard_barrier();
        const bf16x8* Av = (const bf16x8*)(As + sel * BM * 64);
        const bf16x8* Bv = (const bf16x8*)(Bs + sel * BN * 64);
        bf16x8 af[TI][2], bfr[TJ][2];
#pragma unroll
        for (int i = 0; i < TI; i++) {
            int r = wm + i * 16 + l15;
#pragma unroll
            for (int hh = 0; hh < 2; hh++)
                af[i][hh] = Av[r * 8 + ((hh * 4 + quad) ^ (r & 7))];
        }
#pragma unroll
        for (int j = 0; j < TJ; j++) {
            int r = wn + j * 16 + l15;
#pragma unroll
            for (int hh = 0; hh < 2; hh++)
                bfr[j][hh] = Bv[r * 8 + ((hh * 4 + quad) ^ (r & 7))];
        }
#pragma unroll
        for (int hh = 0; hh < 2; hh++)
#pragma unroll
            for (int i = 0; i < TI; i++)
#pragma unroll
                for (int j = 0; j < TJ; j++)
                    acc[i][j] = __builtin_amdgcn_mfma_f32_16x16x32_bf16(
                        af[i][hh], bfr[j][hh], acc[i][j], 0, 0, 0);
        hard_barrier();
    }

    // epilogue: C/D layout col=lane&15, row=quad*4+reg
#pragma unroll
    for (int i = 0; i < TI; i++) {
        int gr = row0 + wm + i * 16 + quad * 4;
#pragma unroll
        for (int j = 0; j < TJ; j++) {
            int gc = col0 + wn + j * 16 + l15;
            float bv = g.bias ? g.bias[gc] : 0.0f;
#pragma unroll
            for (int r = 0; r < 4; r++) {
                float v = acc[i][j][r] + bv;
                if (g.gelu) v = 0.5f * v * (1.0f + erff(v * 0.7071067811865475f));
                g.out[(size_t)(gr + r) * g.N + gc] = __float2bfloat16(v);
            }
        }
    }
}

// ---------------- split-K MFMA GEMM for p2 (BK=64, swizzled): part[z][MP_,768] fp32 ----------------
__global__ __launch_bounds__(256) void mfma_gemm_splitk(
    const bf16* __restrict__ A, const bf16* __restrict__ Wt,
    float* __restrict__ part, int K)
{
    constexpr int BM = 128;
    constexpr int BN = 64;
    constexpr int TI = 4;
    constexpr int TJ = 2;
    constexpr int ABYTES = BM * 128, BBYTES = BN * 128;
    constexpr int AR = 4, BR = 2, NL = 6;
    __shared__ short As[2 * BM * 64];
    __shared__ short Bs[2 * BN * 64];

    int tid = threadIdx.x;
    int wid = tid >> 6;
    int lane = tid & 63;
    int quad = lane >> 4, l15 = lane & 15;
    int row0 = blockIdx.x * BM;
    int col0 = blockIdx.y * BN;
    int wm = (wid >> 1) * 64;
    int wn = (wid & 1) * 32;
    int kh = K >> 1;
    int kbeg = blockIdx.z * kh;

    f32x4 acc[TI][TJ] = {};
    const char* Ab = (const char*)A;
    const char* Wb = (const char*)Wt;
    const size_t Kb = (size_t)K * 2;
    const int base = wid * 1024;

    auto stage = [&](int k0, int sel) {
        char* Ad = (char*)As + sel * ABYTES;
        char* Bd = (char*)Bs + sel * BBYTES;
#pragma unroll
        for (int r = 0; r < AR; r++) {
            int o = r * 4096 + base + lane * 16;
            int row = o >> 7, cs = (o >> 4) & 7;
            int kc = cs ^ (row & 7);
            GL2LDS(Ab + (size_t)(row0 + row) * Kb + (size_t)k0 * 2 + kc * 16, Ad + o);
        }
#pragma unroll
        for (int r = 0; r < BR; r++) {
            int o = r * 4096 + base + lane * 16;
            int row = o >> 7, cs = (o >> 4) & 7;
            int kc = cs ^ (row & 7);
            GL2LDS(Wb + (size_t)(col0 + row) * Kb + (size_t)k0 * 2 + kc * 16, Bd + o);
        }
    };

    const int nk = kh / 64;
    stage(kbeg, 0);
    for (int ki = 0; ki < nk; ki++) {
        int sel = ki & 1;
        if (ki + 1 < nk) {
            stage(kbeg + (ki + 1) * 64, sel ^ 1);
            asm volatile("s_waitcnt vmcnt(%0)" :: "n"(NL) : "memory");
        } else {
            asm volatile("s_waitcnt vmcnt(0)" ::: "memory");
        }
        hard_barrier();
        const bf16x8* Av = (const bf16x8*)(As + sel * BM * 64);
        const bf16x8* Bv = (const bf16x8*)(Bs + sel * BN * 64);
        bf16x8 af[TI][2], bfr[TJ][2];
#pragma unroll
        for (int i = 0; i < TI; i++) {
            int r = wm + i * 16 + l15;
#pragma unroll
            for (int hh = 0; hh < 2; hh++)
                af[i][hh] = Av[r * 8 + ((hh * 4 + quad) ^ (r & 7))];
        }
#pragma unroll
        for (int j = 0; j < TJ; j++) {
            int r = wn + j * 16 + l15;
#pragma unroll
            for (int hh = 0; hh < 2; hh++)
                bfr[j][hh] = Bv[r * 8 + ((hh * 4 + quad) ^ (r & 7))];
        }
#pragma unroll
        for (int hh = 0; hh < 2; hh++)
#pragma unroll
            for (int i = 0; i < TI; i++)
#pragma unroll
                for (int j = 0; j < TJ; j++)
                    acc[i][j] = __builtin_amdgcn_mfma_f32_16x16x32_bf16(
                        af[i][hh], bfr[j][hh], acc[i][j], 0, 0, 0);
        hard_barrier();
    }

    float* outp = part + (size_t)blockIdx.z * MP_ * C_;
#pragma unroll
    for (int i = 0; i < TI; i++) {
        int gr = row0 + wm + i * 16 + quad * 4;
#pragma unroll
        for (int j = 0; j < TJ; j++) {
            int gc = col0 + wn + j * 16 + l15;
#pragma unroll
            for (int r = 0; r < 4; r++)
                outp[(size_t)(gr + r) * C_ + gc] = acc[i][j][r];
        }
    }
}

// ---------------- b2q[n] = q_b[n] + sum_j c_b2[j] * W2q_t[n,j]  (block per n) ----------------
__global__ __launch_bounds__(256) void b2q_kernel(
    const float* __restrict__ c_b2, const float* __restrict__ q_b,
    const bf16* __restrict__ W2q_t, float* __restrict__ b2q)
{
    __shared__ float sdata[256];
    int n = blockIdx.x;
    const bf16* row = W2q_t + (size_t)n * HID_;
    float s = 0.f;
    for (int j = threadIdx.x; j < HID_; j += 256) s += c_b2[j] * b2f(row[j]);
    s = block_reduce_sum256(s, sdata);
    if (threadIdx.x == 0) b2q[n] = s + q_b[n];
}

// ---------------- fused attention + pool + gate ----------------
// block (mt, h, b): K-tile resident; loop n-tiles: scores->sigmoid->PV accum.
__global__ __launch_bounds__(256) void attn_pool_kernel(
    const bf16* __restrict__ q, const bf16* __restrict__ k,
    const bf16* __restrict__ cg, bf16* __restrict__ cbuf,
    float* __restrict__ gate)
{
    int mt = blockIdx.x;
    int h = blockIdx.y, b = blockIdx.z;
    __shared__ float Ks[16][100];
    __shared__ float Qs[16][100];
    __shared__ float Cs[16][100];
    __shared__ float Ps[16][17];
    int tid = threadIdx.x;
    int tn = tid >> 4, tm = tid & 15;        // score mapping
    int pm = tid & 15, dseg = tid >> 4;      // PV mapping: d = dseg*6+j
    const float scale = 0.10206207261596575f; // 96^-0.5

    for (int idx = tid; idx < 16 * 96; idx += 256) {
        int r = idx / 96, c = idx % 96;
        int m = mt * 16 + r;
        Ks[r][c] = (m < M_) ? b2f(k[((size_t)(b * M_ + m)) * C_ + h * D_ + c]) : 0.f;
    }
    float acc[6] = {};
    float gsum = 0.f;
    __syncthreads();

    for (int nt = 0; nt < 13; nt++) {
        for (int idx = tid; idx < 16 * 96; idx += 256) {
            int r = idx / 96, c = idx % 96;
            int n = nt * 16 + r;
            Qs[r][c] = (n < N_) ? b2f(q[((size_t)(b * N_ + n)) * C_ + h * D_ + c]) : 0.f;
            Cs[r][c] = (n < N_) ? b2f(cg[((size_t)(b * N_ + n)) * C_ + h * D_ + c]) : 0.f;
        }
        __syncthreads();
        float s = 0.f;
#pragma unroll 8
        for (int c = 0; c < 96; c++) s += Qs[tn][c] * Ks[tm][c];
        int n = nt * 16 + tn;
        Ps[tn][tm] = (n < N_) ? 1.f / (1.f + expf(-s * scale)) : 0.f;
        __syncthreads();
#pragma unroll
        for (int nn = 0; nn < 16; nn++) {
            float p = Ps[nn][pm];
            if (dseg == 0) gsum += p;
#pragma unroll
            for (int j = 0; j < 6; j++)
                acc[j] += p * Cs[nn][dseg * 6 + j];
        }
        __syncthreads();
    }

    int m = mt * 16 + pm;
    if (m < M_) {
#pragma unroll
        for (int j = 0; j < 6; j++)
            cbuf[((size_t)b * M_ + m) * C_ + h * D_ + dseg * 6 + j] = __float2bfloat16(acc[j]);
        if (dseg == 0) gate[(b * H_ + h) * M_ + m] = 1.f - gsum * (1.f / N_);
    }
}

// ---------------- new_mem = LN(part0+part1+bias + gate*memh) -> mem_bf (+ d_out) ----------------
__global__ __launch_bounds__(256) void final_kernel(
    const float* __restrict__ part, const float* __restrict__ p_b2,
    const float* __restrict__ gate, const bf16* __restrict__ memh,
    const float* __restrict__ w, const float* __restrict__ bia,
    bf16* __restrict__ mem_bf, float* __restrict__ outp)
{
    __shared__ float sdata[256];
    int row = blockIdx.x;
    int b = row / M_, m = row % M_;
    float x[3];
    float sum = 0.f, sumsq = 0.f;
#pragma unroll
    for (int i = 0; i < 3; i++) {
        int c = threadIdx.x + i * 256;
        int h = c / D_;
        float v = part[(size_t)row * C_ + c] + part[(size_t)MP_ * C_ + (size_t)row * C_ + c]
                + p_b2[c]
                + gate[(b * H_ + h) * M_ + m] * b2f(memh[(size_t)row * C_ + c]);
        x[i] = v;
        sum += v; sumsq += v * v;
    }
    sum = block_reduce_sum256(sum, sdata);
    sumsq = block_reduce_sum256(sumsq, sdata);
    float mu = sum * (1.0f / C_);
    float var = sumsq * (1.0f / C_) - mu * mu;
    float rs = rsqrtf(var + 1e-5f);
#pragma unroll
    for (int i = 0; i < 3; i++) {
        int c = threadIdx.x + i * 256;
        float v = (x[i] - mu) * rs * w[c] + bia[c];
        mem_bf[(size_t)row * C_ + c] = __float2bfloat16(v);
        if (outp) outp[(size_t)row * C_ + c] = v;
    }
}

extern "C" void kernel_launch(void* const* d_in, const int* in_sizes, int n_in,
                              void* d_out, int out_size, void* d_ws, size_t ws_size,
                              hipStream_t stream)
{
    const float* cur_fea = (const float*)d_in[0];
    const float* n1w = (const float*)d_in[1];
    const float* n1b = (const float*)d_in[2];
    const float* n2w = (const float*)d_in[3];
    const float* n2b = (const float*)d_in[4];
    const float* c_w1 = (const float*)d_in[5];
    const float* c_b1 = (const float*)d_in[6];
    const float* c_w2 = (const float*)d_in[7];
    const float* c_b2 = (const float*)d_in[8];
    const float* m_w1 = (const float*)d_in[9];
    const float* m_b1 = (const float*)d_in[10];
    const float* m_w2 = (const float*)d_in[11];
    const float* m_b2 = (const float*)d_in[12];
    const float* p_w1 = (const float*)d_in[13];
    const float* p_b1 = (const float*)d_in[14];
    const float* p_w2 = (const float*)d_in[15];
    const float* p_b2 = (const float*)d_in[16];
    const float* q_w = (const float*)d_in[17];
    const float* q_b = (const float*)d_in[18];
    const float* k_w = (const float*)d_in[19];
    const float* k_b = (const float*)d_in[20];

    // ---- workspace carve (256B-aligned) ----
    size_t off = 0;
    char* base = (char*)d_ws;
    auto carve = [&](size_t bytes) -> char* {
        char* r = base + off;
        off += (bytes + 255) & ~(size_t)255;
        return r;
    };
    bf16* cw1t = (bf16*)carve((size_t)HID_ * (2 * C_) * 2);
    bf16* cw2t = (bf16*)carve((size_t)C_ * HID_ * 2);
    bf16* mw1t = (bf16*)carve((size_t)HID_ * C_ * 2);
    bf16* mw2t = (bf16*)carve((size_t)C_ * HID_ * 2);
    bf16* pw1t = (bf16*)carve((size_t)HID_ * C_ * 2);
    bf16* pw2t = (bf16*)carve((size_t)C_ * HID_ * 2);
    bf16* qwt  = (bf16*)carve((size_t)C_ * C_ * 2);
    bf16* kwt  = (bf16*)carve((size_t)C_ * C_ * 2);
    bf16* mem_bf = (bf16*)carve((size_t)MP_ * C_ * 2);
    char* catreg = carve((size_t)MP_ * 2 * C_ * 2);           // cat; later qb|kb
    bf16* cat = (bf16*)catreg;
    bf16* qb  = (bf16*)catreg;                                // alias (cat dead after G1)
    bf16* kb  = (bf16*)catreg + (size_t)MP_ * C_;             // alias (written in G2)
    bf16* hid_c = (bf16*)carve((size_t)MP_ * HID_ * 2);       // c1/p1 out; cw2nt temp pre-loop
    char* hidm_reg = carve((size_t)MP_ * HID_ * 2);           // m1 out; p2 partials
    bf16*  hid_m = (bf16*)hidm_reg;
    float* part  = (float*)hidm_reg;
    bf16* cg    = (bf16*)carve((size_t)MP_ * C_ * 2);
    bf16* cbuf  = (bf16*)carve((size_t)MP_ * C_ * 2);
    bf16* memh  = (bf16*)carve((size_t)MP_ * C_ * 2);
    float* ap   = (float*)carve((size_t)B_ * C_ * 4);
    float* gateb = (float*)carve((size_t)B_ * H_ * M_ * 4);
    float* b2qb  = (float*)carve((size_t)C_ * 4);
    bf16* W2q_t = (bf16*)carve((size_t)C_ * HID_ * 2);
    const bool fuse_q = (off <= ws_size);

    const dim3 blk(256);

    // ---- weight convert + transpose (single batched launch) ----
    {
        TEnts tds;
        tds.e[0] = { c_w1, cw1t, 2 * C_, HID_, (HID_ / 32) * ((2 * C_) / 32) };  // 4608
        tds.e[1] = { c_w2, cw2t, HID_, C_, (C_ / 32) * (HID_ / 32) };            // 2304
        tds.e[2] = { m_w1, mw1t, C_, HID_, (HID_ / 32) * (C_ / 32) };
        tds.e[3] = { m_w2, mw2t, HID_, C_, (C_ / 32) * (HID_ / 32) };
        tds.e[4] = { p_w1, pw1t, C_, HID_, (HID_ / 32) * (C_ / 32) };
        tds.e[5] = { p_w2, pw2t, HID_, C_, (C_ / 32) * (HID_ / 32) };
        tds.e[6] = { q_w, qwt, C_, C_, (C_ / 32) * (C_ / 32) };                  // 576
        tds.e[7] = { k_w, kwt, C_, C_, (C_ / 32) * (C_ / 32) };
        int total = 4608 + 2304 * 5 + 576 * 2;  // 17280
        transpose_all_kernel<<<total, blk, 0, stream>>>(tds);
    }

    if (fuse_q) {
        // W2q_t[n,j] = (c_w2 @ q_w)[j,n]: out = A @ Wt^T, A=qwt[768,768], Wt=cvt(c_w2)[3072,768]
        bf16* cw2nt = hid_c;   // temp, pre-loop only
        cvt_kernel<<<(HID_ * C_ + 255) / 256, blk, 0, stream>>>(c_w2, cw2nt, HID_ * C_);
        GemmDescs ds;
        ds.d[0] = { qwt, cw2nt, nullptr, W2q_t, C_, HID_, HID_ / 128, 0 };
        ds.d[1] = ds.d[0]; ds.d[2] = ds.d[0]; ds.d[3] = ds.d[0];
        mfma_gemm_multi<128><<<dim3(C_ / 128, HID_ / 128, 1), blk, 0, stream>>>(ds);
        b2q_kernel<<<C_, blk, 0, stream>>>(c_b2, q_b, W2q_t, b2qb);
    }

    // ---- init memory = LN(frame 0) ----
    ln_frame_kernel<<<ROWS_, blk, 0, stream>>>(cur_fea, 0, n1w, n1b, mem_bf);

    for (int t = 1; t < T_; t++) {
        ap_kernel<<<B_, 768, 0, stream>>>(mem_bf, ap);
        build_cat_kernel<<<ROWS_, blk, 0, stream>>>(cur_fea, t, n1w, n1b, ap, cat);

        // G1: c1 + m1 (624 blocks). k-proj must NOT be here: kb aliases cat's
        // upper half which c1 is still reading (round-4 race).
        {
            GemmDescs ds;
            ds.d[0] = { cat,    cw1t, c_b1, hid_c, 2 * C_, HID_, HID_ / 128, 1 };
            ds.d[1] = { mem_bf, mw1t, m_b1, hid_m, C_,     HID_, HID_ / 128, 1 };
            ds.d[2] = ds.d[0]; ds.d[3] = ds.d[0];
            mfma_gemm_multi<128><<<dim3(MP_ / 128, HID_ / 128, 2), blk, 0, stream>>>(ds);
        }
        // G2: c2 + m2 + k + fused q (624 blocks). cat dead after G1.
        {
            GemmDescs ds;
            ds.d[0] = { hid_c,  cw2t, c_b2, cg,   HID_, C_, C_ / 64, 0 };
            ds.d[1] = { hid_m,  mw2t, m_b2, memh, HID_, C_, C_ / 64, 0 };
            ds.d[2] = { mem_bf, kwt,  k_b,  kb,   C_,   C_, C_ / 64, 0 };
            ds.d[3] = { hid_c,  W2q_t, b2qb, qb,  HID_, C_, C_ / 64, 0 };
            mfma_gemm_multi<64><<<dim3(MP_ / 128, C_ / 64, fuse_q ? 4 : 3), blk, 0, stream>>>(ds);
        }
        if (!fuse_q) {
            GemmDescs ds;
            ds.d[0] = { cg, qwt, q_b, qb, C_, C_, C_ / 64, 0 };
            ds.d[1] = ds.d[0]; ds.d[2] = ds.d[0]; ds.d[3] = ds.d[0];
            mfma_gemm_multi<64><<<dim3(MP_ / 128, C_ / 64, 1), blk, 0, stream>>>(ds);
        }
        // fused attention + pool + gate (832 blocks)
        attn_pool_kernel<<<dim3(13, H_, B_), blk, 0, stream>>>(qb, kb, cg, cbuf, gateb);
        // p1 (BN=64 for occupancy: 624 blocks) into hid_c
        {
            GemmDescs ds;
            ds.d[0] = { cbuf, pw1t, p_b1, hid_c, C_, HID_, HID_ / 64, 1 };
            ds.d[1] = ds.d[0]; ds.d[2] = ds.d[0]; ds.d[3] = ds.d[0];
            mfma_gemm_multi<64><<<dim3(MP_ / 128, HID_ / 64, 1), blk, 0, stream>>>(ds);
        }
        // p2 split-K=2 -> fp32 partials (hidm_reg free: m1-out consumed by G2)
        mfma_gemm_splitk<<<dim3(MP_ / 128, C_ / 64, 2), blk, 0, stream>>>(hid_c, pw2t, part, HID_);
        // residual gate + LN -> new mem
        final_kernel<<<ROWS_, blk, 0, stream>>>(part, p_b2, gateb, memh, n2w, n2b,
                                                mem_bf, (t == T_ - 1) ? (float*)d_out : nullptr);
    }
}